// Round 1
// baseline (2189.773 us; speedup 1.0000x reference)
//
#include <hip/hip_runtime.h>

// Problem constants
#define NB    128
#define NC    256
#define NPOS  196
#define NHEAD 8
#define NAG   49
#define YSTR  150528      // 768*196 per-batch y floats
#define VOFF  50176       // v_raw offset inside y (256*196)
#define QOFF  100352      // q_raw offset inside y (512*196)
#define SCL   0.17677669529663687f   // 32^-0.5

// Workspace layout (floats). Total = 38,885,440 floats = 155.5 MB.
#define WS_Y    0u
#define WS_V5   19267584u
#define WS_AT   25690112u
#define WS_ATK  27295744u
#define WS_CHG  28901376u
#define WS_CMAP 28934144u
#define WS_PBT  28966912u
#define WS_AB   29043744u
#define WS_X1S  29120576u
#define WS_AGV  29153344u
#define WS_XO   30758976u
#define WS_WT   37181504u
#define WS_CWT  37247040u

__device__ __forceinline__ float sigmoidf_(float x){ return 1.0f/(1.0f+__expf(-x)); }

// bilinear upsample 7x7 -> 14x14 sample at (i,j), matching reference grid()
__device__ __forceinline__ float bilin7(const float* __restrict__ src, int i, int j){
  float pi = fmaxf(0.5f*(float)i - 0.25f, 0.f);
  int i0 = (int)pi; if (i0 > 6) i0 = 6;
  int i1 = i0 + 1;  if (i1 > 6) i1 = 6;
  float li = pi - (float)i0;
  float pj = fmaxf(0.5f*(float)j - 0.25f, 0.f);
  int j0 = (int)pj; if (j0 > 6) j0 = 6;
  int j1 = j0 + 1;  if (j1 > 6) j1 = 6;
  float lj = pj - (float)j0;
  float v00 = src[i0*7+j0], v01 = src[i0*7+j1];
  float v10 = src[i1*7+j0], v11 = src[i1*7+j1];
  float t0 = v00*(1.f-lj) + v01*lj;
  float t1 = v10*(1.f-lj) + v11*lj;
  return t0*(1.f-li) + t1*li;
}

// 5x5 conv over a zero-padded [18][20] plane, producing one 14-wide output row r.
__device__ __forceinline__ void conv5x5_row(const float* __restrict__ plane, int r,
                                            const float* __restrict__ w25, float* acc14){
  #pragma unroll
  for (int di = 0; di < 5; ++di){
    const float4* pr = (const float4*)(plane + (r+di)*20);
    float4 p0 = pr[0], p1 = pr[1], p2 = pr[2], p3 = pr[3], p4 = pr[4];
    float row[20] = {p0.x,p0.y,p0.z,p0.w, p1.x,p1.y,p1.z,p1.w, p2.x,p2.y,p2.z,p2.w,
                     p3.x,p3.y,p3.z,p3.w, p4.x,p4.y,p4.z,p4.w};
    #pragma unroll
    for (int dj = 0; dj < 5; ++dj){
      float w = w25[di*5+dj];
      #pragma unroll
      for (int j = 0; j < 14; ++j) acc14[j] = fmaf(row[j+dj], w, acc14[j]);
    }
  }
}

// ---------- prep kernels ----------
__global__ void k_pb(const float* __restrict__ an, const float* __restrict__ ah,
                     const float* __restrict__ aw, float* __restrict__ PBT){
  int t = blockIdx.x*256 + threadIdx.x;
  if (t >= NHEAD*NPOS*NAG) return;
  int a = t % NAG;
  int r = t / NAG;
  int n = r % NPOS;
  int h = r / NPOS;
  int i = n/14, j = n - (n/14)*14;
  float v = bilin7(an + ((size_t)h*NAG + a)*49, i, j);
  v += ah[((size_t)h*NAG + a)*14 + i] + aw[((size_t)h*NAG + a)*14 + j];
  PBT[t] = v;   // [h][n][a]
}

__global__ void k_ab(const float* __restrict__ na, const float* __restrict__ ha,
                     const float* __restrict__ wa, float* __restrict__ AB){
  int t = blockIdx.x*256 + threadIdx.x;
  if (t >= NHEAD*NPOS*NAG) return;
  int a = t % NAG;
  int r = t / NAG;
  int n = r % NPOS;
  int h = r / NPOS;
  int i = n/14, j = n - (n/14)*14;
  float v = bilin7(na + ((size_t)h*NAG + a)*49, i, j);
  v += ha[((size_t)h*14 + i)*NAG + a] + wa[((size_t)h*14 + j)*NAG + a];
  AB[t] = v;    // [h][n][a]
}

__global__ void k_wt(const float* __restrict__ pw, float* __restrict__ WT){
  int t = blockIdx.x*256 + threadIdx.x;
  if (t >= 65536) return;
  int k = t >> 8, c = t & 255;
  WT[t] = pw[c*256 + k];          // WT[k][c] = proj_w[c][k]
}

__global__ void k_cwt(const float* __restrict__ cw, float* __restrict__ CWT){
  int t = blockIdx.x*256 + threadIdx.x;
  if (t >= 1638400) return;
  int co = t & 255;
  int r  = t >> 8;                // ci*25 + u
  int ci = r/25, u = r - ci*25;
  CWT[t] = cw[((size_t)co*256 + ci)*25 + u];   // CWT[ci][tap][co]
}

// ---------- lka depthwise-ish conv (groups=256, 3 outputs per input channel) ----------
__global__ __launch_bounds__(256) void k_lka(const float* __restrict__ x, const float* __restrict__ lw,
                                             const float* __restrict__ lb, float* __restrict__ Y){
  int b = blockIdx.x >> 3, gb = blockIdx.x & 7;
  int g0 = gb*32;                               // input channels [g0,g0+32)
  __shared__ __align__(16) float pl[32*360];    // [ch][18*20] padded planes
  int tid = threadIdx.x;
  for (int t = tid; t < 32*360; t += 256) pl[t] = 0.f;
  __syncthreads();
  for (int t = tid; t < 32*196; t += 256){
    int gl = t & 31, s = t >> 5;
    int i = s/14, j = s - i*14;
    pl[gl*360 + (i+2)*20 + j + 2] = x[((size_t)b*196 + s)*256 + g0 + gl];
  }
  __syncthreads();
  for (int t = tid; t < 96*14; t += 256){
    int ocl = t/14, r = t - ocl*14;
    int o  = g0*3 + ocl;          // output channel; uses input channel o/3
    int gl = ocl/3;
    float w25[25];
    #pragma unroll
    for (int u = 0; u < 25; ++u) w25[u] = lw[o*25 + u];
    float acc[14];
    float bv = lb[o];
    #pragma unroll
    for (int j = 0; j < 14; ++j) acc[j] = bv;
    conv5x5_row(&pl[gl*360], r, w25, acc);
    float* dst = Y + ((size_t)b*768 + o)*196 + r*14;
    #pragma unroll
    for (int j = 0; j < 14; ++j) dst[j] = acc[j];
  }
}

// ---------- conv5: full 256->256 5x5 conv on v_raw, stores into scrambled v5 layout ----------
__global__ __launch_bounds__(256) void k_conv5(const float* __restrict__ Y, const float* __restrict__ CWT,
                                               const float* __restrict__ cb, float* __restrict__ V5){
  int b = blockIdx.x >> 2, cog = blockIdx.x & 3;
  int co0 = cog*64;                      // 64 output channels per block, 4 per thread
  __shared__ __align__(16) float pl[18*20];
  __shared__ __align__(16) float wt[25*64];   // [tap][co_local]
  int tid = threadIdx.x;
  int col = tid >> 4;                    // 0..15
  int rr  = tid & 15;                    // output row (active if <14)
  float acc[4][14];
  #pragma unroll
  for (int q = 0; q < 4; ++q)
    #pragma unroll
    for (int j = 0; j < 14; ++j) acc[q][j] = 0.f;
  for (int t = tid; t < 360; t += 256) pl[t] = 0.f;
  __syncthreads();
  const float* src = Y + ((size_t)b*768 + 256)*196;   // v_raw
  for (int ci = 0; ci < 256; ++ci){
    if (tid < 196){
      int i = tid/14, j = tid - i*14;
      pl[(i+2)*20 + j + 2] = src[ci*196 + tid];
    }
    const float* wsrc = CWT + (size_t)ci*6400 + co0;
    for (int t = tid; t < 1600; t += 256){
      int u = t >> 6, q = t & 63;
      wt[t] = wsrc[u*256 + q];
    }
    __syncthreads();
    if (rr < 14){
      #pragma unroll
      for (int di = 0; di < 5; ++di){
        const float4* pr = (const float4*)(pl + (rr+di)*20);
        float4 p0 = pr[0], p1 = pr[1], p2 = pr[2], p3 = pr[3], p4 = pr[4];
        float row[20] = {p0.x,p0.y,p0.z,p0.w, p1.x,p1.y,p1.z,p1.w, p2.x,p2.y,p2.z,p2.w,
                         p3.x,p3.y,p3.z,p3.w, p4.x,p4.y,p4.z,p4.w};
        #pragma unroll
        for (int dj = 0; dj < 5; ++dj){
          float4 w4 = *(const float4*)(wt + (di*5+dj)*64 + col*4);
          #pragma unroll
          for (int j = 0; j < 14; ++j){
            float xv = row[j+dj];
            acc[0][j] = fmaf(xv, w4.x, acc[0][j]);
            acc[1][j] = fmaf(xv, w4.y, acc[1][j]);
            acc[2][j] = fmaf(xv, w4.z, acc[2][j]);
            acc[3][j] = fmaf(xv, w4.w, acc[3][j]);
          }
        }
      }
    }
    __syncthreads();
  }
  if (rr < 14){
    #pragma unroll
    for (int q = 0; q < 4; ++q){
      int co = co0 + col*4 + q;
      float bv = cb[co];
      int f0 = co*196 + rr*14;
      #pragma unroll
      for (int j = 0; j < 14; ++j){
        int f = f0 + j;   // v5[b, f%256, f/256] = z[b, f]
        V5[((size_t)b*256 + (f & 255))*196 + (f >> 8)] = acc[q][j] + bv;
      }
    }
  }
}

// ---------- agent token pooling: at = 2x2-mean of q_raw, atk = 2x2-max of k_raw ----------
__global__ __launch_bounds__(256) void k_pool(const float* __restrict__ Y, float* __restrict__ AT, float* __restrict__ ATK){
  int b = blockIdx.x; int c = threadIdx.x;
  const float* qp = Y + ((size_t)b*768 + 512 + c)*196;
  const float* kp = Y + ((size_t)b*768 + c)*196;
  for (int a = 0; a < 49; ++a){
    int p1 = a/7, p2 = a - p1*7;
    int s = p1*28 + p2*2;
    float q0 = qp[s], q1 = qp[s+1], q2 = qp[s+14], q3 = qp[s+15];
    AT[((size_t)b*49 + a)*256 + c] = 0.25f*(q0+q1+q2+q3);
    float k0 = kp[s], k1 = kp[s+1], k2 = kp[s+14], k3 = kp[s+15];
    ATK[((size_t)b*49 + a)*256 + c] = fmaxf(fmaxf(k0,k1), fmaxf(k2,k3));
  }
}

// ---------- cbam stage A: channel gate ----------
__global__ __launch_bounds__(256) void k_cbam_a(const float* __restrict__ V5,
    const float* __restrict__ caa1w, const float* __restrict__ caa1b,
    const float* __restrict__ caa2w, const float* __restrict__ caa2b,
    const float* __restrict__ cam1w, const float* __restrict__ cam1b,
    const float* __restrict__ cam2w, const float* __restrict__ cam2b,
    float* __restrict__ CHG){
  int b = blockIdx.x, c = threadIdx.x;
  __shared__ float avg[256], mx[256], t1[16], t2[16];
  const float* pp = V5 + ((size_t)b*256 + c)*196;
  float s = 0.f, m = -1e30f;
  for (int i = 0; i < 196; ++i){ float v = pp[i]; s += v; m = fmaxf(m, v); }
  avg[c] = s * (1.0f/196.0f); mx[c] = m;
  __syncthreads();
  if (c < 16){
    float a1 = caa1b[c], a2 = cam1b[c];
    #pragma unroll 4
    for (int k = 0; k < 256; ++k){
      a1 = fmaf(caa1w[(c*256 + k)*9 + 4], avg[k], a1);   // 3x3 center tap
      a2 = fmaf(cam1w[c*256 + k], mx[k], a2);            // 1x1
    }
    t1[c] = fmaxf(a1, 0.f);
    t2[c] = fmaxf(a2, 0.f);
  }
  __syncthreads();
  float y1 = caa2b[c], y2 = cam2b[c];
  #pragma unroll
  for (int k = 0; k < 16; ++k){
    y1 = fmaf(caa2w[(c*16 + k)*9 + 4], t1[k], y1);
    y2 = fmaf(cam2w[c*16 + k], t2[k], y2);
  }
  CHG[b*256 + c] = sigmoidf_(sigmoidf_(y1) + sigmoidf_(y2));
}

// ---------- cbam stage B: spatial mask (9x9 pad4 over [mean,max]) + in-place gate ----------
__global__ __launch_bounds__(256) void k_cbam_b(float* __restrict__ V5, const float* __restrict__ CHG,
    const float* __restrict__ saw, const float* __restrict__ sab){
  int b = blockIdx.x; int tid = threadIdx.x;
  __shared__ float chg[256];
  __shared__ float mp[22*22], xp[22*22];
  __shared__ float mk[196];
  chg[tid] = CHG[b*256 + tid];
  for (int t = tid; t < 484; t += 256){ mp[t] = 0.f; xp[t] = 0.f; }
  __syncthreads();
  if (tid < 196){
    int i = tid/14, j = tid - i*14;
    float s = 0.f, m = -1e30f;
    const float* vb = V5 + (size_t)b*256*196 + tid;
    for (int c = 0; c < 256; ++c){
      float v = chg[c] * vb[c*196];
      s += v; m = fmaxf(m, v);
    }
    mp[(i+4)*22 + j+4] = s*(1.f/256.f);
    xp[(i+4)*22 + j+4] = m;
  }
  __syncthreads();
  if (tid < 196){
    int i = tid/14, j = tid - i*14;
    float acc = sab[0];
    for (int di = 0; di < 9; ++di){
      #pragma unroll
      for (int dj = 0; dj < 9; ++dj){
        acc = fmaf(mp[(i+di)*22 + j+dj], saw[di*9+dj], acc);
        acc = fmaf(xp[(i+di)*22 + j+dj], saw[81 + di*9+dj], acc);
      }
    }
    mk[tid] = sigmoidf_(acc);
  }
  __syncthreads();
  if (tid < 196){
    float m = mk[tid];
    float* vb = V5 + (size_t)b*256*196 + tid;
    for (int c = 0; c < 256; ++c) vb[c*196] = chg[c]*vb[c*196]*m;
  }
}

// ---------- big NxN attention; only the per-(b,c) mean of x1 is needed downstream ----------
__global__ __launch_bounds__(256) void k_attn(const float* __restrict__ Y, const float* __restrict__ rpbt,
                                              float* __restrict__ X1S){
  int b = blockIdx.x >> 3, h = blockIdx.x & 7;
  __shared__ float rp[729];
  __shared__ float xs[196*33];
  int tid = threadIdx.x;
  for (int t = tid; t < 729; t += 256) rp[t] = rpbt[t*8 + h];
  __syncthreads();
  const float* yb = Y + (size_t)b*YSTR;
  if (tid < 196){
    int n = tid;
    float q[32];
    {
      const float4* q4 = (const float4*)(yb + QOFF + (size_t)n*256 + h*32);
      #pragma unroll
      for (int u = 0; u < 8; ++u){
        float4 v = q4[u];
        q[4*u] = v.x*SCL; q[4*u+1] = v.y*SCL; q[4*u+2] = v.z*SCL; q[4*u+3] = v.w*SCL;
      }
    }
    int ri = n/14, ci = n - ri*14;
    int bidx = (ri + 13)*27 + (ci + 13);
    float acc[32];
    #pragma unroll
    for (int d = 0; d < 32; ++d) acc[d] = 0.f;
    float l = 0.f;
    int rj = 0, cj = 0;
    for (int j = 0; j < 196; ++j){
      const float4* k4 = (const float4*)(yb + (size_t)j*256 + h*32);
      float s0 = 0.f, s1 = 0.f;
      #pragma unroll
      for (int u = 0; u < 8; u += 2){
        float4 a = k4[u], bb = k4[u+1];
        s0 = fmaf(q[4*u+0],a.x, fmaf(q[4*u+1],a.y, fmaf(q[4*u+2],a.z, fmaf(q[4*u+3],a.w, s0))));
        s1 = fmaf(q[4*u+4],bb.x, fmaf(q[4*u+5],bb.y, fmaf(q[4*u+6],bb.z, fmaf(q[4*u+7],bb.w, s1))));
      }
      float s = s0 + s1 + rp[bidx - rj*27 - cj];
      float p = __expf(s);       // logits are O(0.1): max-free softmax is safe
      l += p;
      const float4* v4 = (const float4*)(yb + VOFF + (size_t)j*256 + h*32);
      #pragma unroll
      for (int u = 0; u < 8; ++u){
        float4 vv = v4[u];
        acc[4*u]   = fmaf(p, vv.x, acc[4*u]);
        acc[4*u+1] = fmaf(p, vv.y, acc[4*u+1]);
        acc[4*u+2] = fmaf(p, vv.z, acc[4*u+2]);
        acc[4*u+3] = fmaf(p, vv.w, acc[4*u+3]);
      }
      if (++cj == 14){ cj = 0; ++rj; }
    }
    float inv = 1.f/l;
    #pragma unroll
    for (int d = 0; d < 32; ++d) xs[n*33 + d] = acc[d]*inv;
  }
  __syncthreads();
  if (tid < 32){
    float s = 0.f;
    for (int n = 0; n < 196; ++n) s += xs[n*33 + tid];
    X1S[(size_t)b*256 + h*32 + tid] = s*(1.f/196.f);   // mean over n of x1[b,:,c]
  }
}

// ---------- chan_inter on x1 mean -> sigmoid gate CMAP ----------
__global__ __launch_bounds__(256) void k_cinter(const float* __restrict__ X1S,
    const float* __restrict__ ci1w, const float* __restrict__ ci1b,
    const float* __restrict__ bng, const float* __restrict__ bnb,
    const float* __restrict__ ci2w, const float* __restrict__ ci2b, float* __restrict__ CMAP){
  int b = blockIdx.x, c = threadIdx.x;
  __shared__ float p[256], tt[16];
  p[c] = X1S[b*256 + c];
  __syncthreads();
  if (c < 16){
    float a = ci1b[c];
    #pragma unroll 4
    for (int k = 0; k < 256; ++k) a = fmaf(ci1w[(c*256+k)*25 + 12], p[k], a);  // 5x5 center
    const float invs = 0.9999950000375f;   // 1/sqrt(1+1e-5)
    tt[c] = fmaxf(fmaf(bng[c]*invs, a, bnb[c]), 0.f);
  }
  __syncthreads();
  float a = ci2b[c];
  #pragma unroll
  for (int k = 0; k < 16; ++k) a = fmaf(ci2w[(c*16+k)*25 + 12], tt[k], a);
  CMAP[b*256 + c] = sigmoidf_(a);
}

// ---------- agent_v = softmax(at*scale@K^T+pb)@V1 + softmax(atk*scale@Q^T+pb)@V ----------
__global__ __launch_bounds__(256) void k_agentv(const float* __restrict__ Y, const float* __restrict__ V5,
    const float* __restrict__ AT, const float* __restrict__ ATK,
    const float* __restrict__ PBT, float* __restrict__ AGV){
  int b = blockIdx.x >> 3, h = blockIdx.x & 7;
  __shared__ float S[196*53];
  __shared__ float part[4*64];
  int tid = threadIdx.x;
  int wv = tid >> 6, lane = tid & 63;
  const float* yb  = Y + (size_t)b*YSTR;
  const float* vcb = V5 + (size_t)b*256*196;
  float ar[32], akr[32];
  if (lane < 49){
    const float4* ap = (const float4*)(AT  + ((size_t)b*49 + lane)*256 + h*32);
    const float4* kp = (const float4*)(ATK + ((size_t)b*49 + lane)*256 + h*32);
    #pragma unroll
    for (int u = 0; u < 8; ++u){
      float4 a = ap[u], k = kp[u];
      ar[4*u]=a.x; ar[4*u+1]=a.y; ar[4*u+2]=a.z; ar[4*u+3]=a.w;
      akr[4*u]=k.x; akr[4*u+1]=k.y; akr[4*u+2]=k.z; akr[4*u+3]=k.w;
    }
  }
  float acc[8];
  #pragma unroll
  for (int d = 0; d < 8; ++d) acc[d] = 0.f;
  int d0 = wv*8;

  // ---- pass 0: agent_attn (ar . K)*scale + pb ; x V1 (vc) ----
  {
    float lsum = 0.f;
    if (lane < 49){
      for (int n = wv; n < 196; n += 4){
        const float4* r4 = (const float4*)(yb + (size_t)n*256 + h*32);
        float s = 0.f;
        #pragma unroll
        for (int u = 0; u < 8; ++u){
          float4 v = r4[u];
          s = fmaf(ar[4*u],v.x, fmaf(ar[4*u+1],v.y, fmaf(ar[4*u+2],v.z, fmaf(ar[4*u+3],v.w, s))));
        }
        s = fmaf(s, SCL, PBT[((size_t)h*196 + n)*49 + lane]);
        float e = __expf(s);
        S[n*53 + lane] = e;
        lsum += e;
      }
    }
    part[wv*64 + lane] = lsum;
    __syncthreads();
    if (lane < 49){
      float l = part[lane] + part[64+lane] + part[128+lane] + part[192+lane];
      float inv = 1.f/l;
      float a8[8];
      #pragma unroll
      for (int d = 0; d < 8; ++d) a8[d] = 0.f;
      const float* vp = vcb + (h*32 + d0)*196;
      for (int n = 0; n < 196; ++n){
        float pv = S[n*53 + lane];
        #pragma unroll
        for (int d = 0; d < 8; ++d) a8[d] = fmaf(pv, vp[d*196 + n], a8[d]);
      }
      #pragma unroll
      for (int d = 0; d < 8; ++d) acc[d] += inv*a8[d];
    }
    __syncthreads();
  }
  // ---- pass 1: agent_attn1 (akr . Q_raw)*scale^2 + pb ; x V (y) ----
  {
    float lsum = 0.f;
    if (lane < 49){
      for (int n = wv; n < 196; n += 4){
        const float4* r4 = (const float4*)(yb + QOFF + (size_t)n*256 + h*32);
        float s = 0.f;
        #pragma unroll
        for (int u = 0; u < 8; ++u){
          float4 v = r4[u];
          s = fmaf(akr[4*u],v.x, fmaf(akr[4*u+1],v.y, fmaf(akr[4*u+2],v.z, fmaf(akr[4*u+3],v.w, s))));
        }
        s = fmaf(s, 0.03125f, PBT[((size_t)h*196 + n)*49 + lane]);
        float e = __expf(s);
        S[n*53 + lane] = e;
        lsum += e;
      }
    }
    part[wv*64 + lane] = lsum;
    __syncthreads();
    if (lane < 49){
      float l = part[lane] + part[64+lane] + part[128+lane] + part[192+lane];
      float inv = 1.f/l;
      float a8[8];
      #pragma unroll
      for (int d = 0; d < 8; ++d) a8[d] = 0.f;
      for (int n = 0; n < 196; ++n){
        float pv = S[n*53 + lane];
        const float* vp = yb + VOFF + (size_t)n*256 + h*32 + d0;
        #pragma unroll
        for (int d = 0; d < 8; ++d) a8[d] = fmaf(pv, vp[d], a8[d]);
      }
      #pragma unroll
      for (int d = 0; d < 8; ++d) acc[d] += inv*a8[d];
    }
  }
  if (lane < 49){
    float* dst = AGV + (((size_t)(b*8 + h)*49) + lane)*32 + d0;
    #pragma unroll
    for (int d = 0; d < 8; ++d) dst[d] = acc[d];
  }
}

// ---------- xo1 = (softmax(q*scale@at^T+ab) + softmax(k*scale@atk^T+ab)) @ agent_v ----------
__global__ __launch_bounds__(128) void k_xo1(const float* __restrict__ Y,
    const float* __restrict__ AT, const float* __restrict__ ATK,
    const float* __restrict__ AB, const float* __restrict__ AGV, float* __restrict__ XO){
  int b = blockIdx.x >> 3, h = blockIdx.x & 7;
  __shared__ float Pq[98*53], Pk[98*53];
  __shared__ float sq[98], sk[98];
  int tid = threadIdx.x;
  int wv = tid >> 6, lane = tid & 63;
  const float* yb = Y + (size_t)b*YSTR;
  float ar[32], akr[32];
  if (lane < 49){
    const float4* ap = (const float4*)(AT  + ((size_t)b*49 + lane)*256 + h*32);
    const float4* kp = (const float4*)(ATK + ((size_t)b*49 + lane)*256 + h*32);
    #pragma unroll
    for (int u = 0; u < 8; ++u){
      float4 a = ap[u], k = kp[u];
      ar[4*u]=a.x; ar[4*u+1]=a.y; ar[4*u+2]=a.z; ar[4*u+3]=a.w;
      akr[4*u]=k.x; akr[4*u+1]=k.y; akr[4*u+2]=k.z; akr[4*u+3]=k.w;
    }
  }
  const float* agvb = AGV + (size_t)(b*8 + h)*49*32;
  for (int chunk = 0; chunk < 2; ++chunk){
    int n0 = chunk*98;
    // q-attn logits (q_raw . at)*scale^2 + ab
    for (int nn = wv; nn < 98; nn += 2){
      int n = n0 + nn;
      float e = 0.f;
      if (lane < 49){
        const float4* r4 = (const float4*)(yb + QOFF + (size_t)n*256 + h*32);
        float s = 0.f;
        #pragma unroll
        for (int u = 0; u < 8; ++u){
          float4 v = r4[u];
          s = fmaf(ar[4*u],v.x, fmaf(ar[4*u+1],v.y, fmaf(ar[4*u+2],v.z, fmaf(ar[4*u+3],v.w, s))));
        }
        s = fmaf(s, 0.03125f, AB[((size_t)h*196 + n)*49 + lane]);
        e = __expf(s);
        Pq[nn*53 + lane] = e;
      }
      float t = e;
      #pragma unroll
      for (int o = 32; o > 0; o >>= 1) t += __shfl_xor(t, o);
      if (lane == 0) sq[nn] = t;
    }
    // k-attn logits (k_raw . atk)*scale + ab
    for (int nn = wv; nn < 98; nn += 2){
      int n = n0 + nn;
      float e = 0.f;
      if (lane < 49){
        const float4* r4 = (const float4*)(yb + (size_t)n*256 + h*32);
        float s = 0.f;
        #pragma unroll
        for (int u = 0; u < 8; ++u){
          float4 v = r4[u];
          s = fmaf(akr[4*u],v.x, fmaf(akr[4*u+1],v.y, fmaf(akr[4*u+2],v.z, fmaf(akr[4*u+3],v.w, s))));
        }
        s = fmaf(s, SCL, AB[((size_t)h*196 + n)*49 + lane]);
        e = __expf(s);
        Pk[nn*53 + lane] = e;
      }
      float t = e;
      #pragma unroll
      for (int o = 32; o > 0; o >>= 1) t += __shfl_xor(t, o);
      if (lane == 0) sk[nn] = t;
    }
    __syncthreads();
    if (tid < 98){
      int n = n0 + tid;
      float invq = 1.f/sq[tid], invk = 1.f/sk[tid];
      float out[32];
      #pragma unroll
      for (int d = 0; d < 32; ++d) out[d] = 0.f;
      for (int a = 0; a < 49; ++a){
        float pv = Pq[tid*53 + a]*invq + Pk[tid*53 + a]*invk;
        const float4* g4 = (const float4*)(agvb + a*32);
        #pragma unroll
        for (int u = 0; u < 8; ++u){
          float4 gv = g4[u];
          out[4*u]   = fmaf(pv, gv.x, out[4*u]);
          out[4*u+1] = fmaf(pv, gv.y, out[4*u+1]);
          out[4*u+2] = fmaf(pv, gv.z, out[4*u+2]);
          out[4*u+3] = fmaf(pv, gv.w, out[4*u+3]);
        }
      }
      float* dst = XO + ((size_t)b*196 + n)*256 + h*32;
      #pragma unroll
      for (int d = 0; d < 32; ++d) dst[d] = out[d];
    }
    __syncthreads();
  }
}

// ---------- fused depthwise conv: dwc(conv_x2 + qc), bias 2*dwc_b, accumulated into XO ----------
__global__ __launch_bounds__(256) void k_dwc(const float* __restrict__ Y, const float* __restrict__ CMAP,
    const float* __restrict__ dw, const float* __restrict__ db, float* __restrict__ XO){
  int b = blockIdx.x >> 3, cg = blockIdx.x & 7;
  int c0 = cg*32;
  __shared__ __align__(16) float pl[32*360];
  int tid = threadIdx.x;
  for (int t = tid; t < 32*360; t += 256) pl[t] = 0.f;
  __syncthreads();
  const float* yq = Y + (size_t)b*YSTR + QOFF;
  for (int t = tid; t < 32*196; t += 256){
    int cl = t & 31, s = t >> 5;
    int c = c0 + cl;
    int G = s*256 + c;                 // head-major flat index for conv_x2's scramble
    int hh = G / 6272;
    int rem = G - hh*6272;
    int n = rem >> 5, d = rem & 31;
    float cx2 = CMAP[b*256 + c] * yq[n*256 + hh*32 + d];   // sigmoid(cmap)*qs
    float qc  = yq[G];                                     // qc collapses to identity gather
    float v = SCL*(cx2 + qc);
    int i = s/14, j = s - i*14;
    pl[cl*360 + (i+2)*20 + j + 2] = v;
  }
  __syncthreads();
  for (int t = tid; t < 32*14; t += 256){
    int cl = t/14, r = t - cl*14;
    int c = c0 + cl;
    float w25[25];
    #pragma unroll
    for (int u = 0; u < 25; ++u) w25[u] = dw[c*25 + u];
    float acc[14];
    float b2 = 2.f*db[c];
    #pragma unroll
    for (int j = 0; j < 14; ++j) acc[j] = b2;
    conv5x5_row(&pl[cl*360], r, w25, acc);
    float* dst = XO + ((size_t)b*196 + r*14)*256 + c;
    #pragma unroll
    for (int j = 0; j < 14; ++j) dst[j*256] += acc[j];
  }
}

// ---------- final projection: out = XO @ proj_w^T + proj_b ----------
__global__ __launch_bounds__(256) void k_proj(const float* __restrict__ XO, const float* __restrict__ WT,
    const float* __restrict__ pbias, float* __restrict__ OUT){
  int bb = blockIdx.x / 7, nt = blockIdx.x % 7;
  int n0 = nt*28;
  int c = threadIdx.x;
  const float* xb = XO + ((size_t)bb*196 + n0)*256;
  float acc[28];
  #pragma unroll
  for (int r = 0; r < 28; ++r) acc[r] = 0.f;
  for (int k = 0; k < 256; k += 4){
    float w0 = WT[(k+0)*256 + c];
    float w1 = WT[(k+1)*256 + c];
    float w2 = WT[(k+2)*256 + c];
    float w3 = WT[(k+3)*256 + c];
    #pragma unroll
    for (int r = 0; r < 28; ++r){
      float4 xv = *(const float4*)(xb + r*256 + k);   // uniform address -> scalar/L1 path
      acc[r] = fmaf(xv.x, w0, fmaf(xv.y, w1, fmaf(xv.z, w2, fmaf(xv.w, w3, acc[r]))));
    }
  }
  float bv = pbias[c];
  float* dst = OUT + ((size_t)bb*196 + n0)*256 + c;
  #pragma unroll
  for (int r = 0; r < 28; ++r) dst[r*256] = acc[r] + bv;
}

extern "C" void kernel_launch(void* const* d_in, const int* in_sizes, int n_in,
                              void* d_out, int out_size, void* d_ws, size_t ws_size,
                              hipStream_t stream){
  (void)in_sizes; (void)n_in; (void)out_size; (void)ws_size;
  const float* x       = (const float*)d_in[0];
  const float* lka_w   = (const float*)d_in[3];
  const float* lka_b   = (const float*)d_in[4];
  const float* conv5_w = (const float*)d_in[5];
  const float* conv5_b = (const float*)d_in[6];
  const float* caa1_w  = (const float*)d_in[7];
  const float* caa1_b  = (const float*)d_in[8];
  const float* caa2_w  = (const float*)d_in[9];
  const float* caa2_b  = (const float*)d_in[10];
  const float* cam1_w  = (const float*)d_in[11];
  const float* cam1_b  = (const float*)d_in[12];
  const float* cam2_w  = (const float*)d_in[13];
  const float* cam2_b  = (const float*)d_in[14];
  const float* sa_w    = (const float*)d_in[15];
  const float* sa_b    = (const float*)d_in[16];
  const float* ci1_w   = (const float*)d_in[17];
  const float* ci1_b   = (const float*)d_in[18];
  const float* bn_g    = (const float*)d_in[19];
  const float* bn_b    = (const float*)d_in[20];
  const float* ci2_w   = (const float*)d_in[21];
  const float* ci2_b   = (const float*)d_in[22];
  const float* rpbt    = (const float*)d_in[23];
  const float* an_bias = (const float*)d_in[24];
  const float* na_bias = (const float*)d_in[25];
  const float* ah_bias = (const float*)d_in[26];
  const float* aw_bias = (const float*)d_in[27];
  const float* ha_bias = (const float*)d_in[28];
  const float* wa_bias = (const float*)d_in[29];
  const float* dwc_w   = (const float*)d_in[30];
  const float* dwc_b   = (const float*)d_in[31];
  const float* proj_w  = (const float*)d_in[32];
  const float* proj_b  = (const float*)d_in[33];
  float* out = (float*)d_out;
  float* ws = (float*)d_ws;

  float* Y    = ws + WS_Y;
  float* V5   = ws + WS_V5;
  float* AT   = ws + WS_AT;
  float* ATK  = ws + WS_ATK;
  float* CHG  = ws + WS_CHG;
  float* CMAP = ws + WS_CMAP;
  float* PBT  = ws + WS_PBT;
  float* AB   = ws + WS_AB;
  float* X1S  = ws + WS_X1S;
  float* AGV  = ws + WS_AGV;
  float* XO   = ws + WS_XO;
  float* WT   = ws + WS_WT;
  float* CWT  = ws + WS_CWT;

  k_pb   <<<301, 256, 0, stream>>>(an_bias, ah_bias, aw_bias, PBT);
  k_ab   <<<301, 256, 0, stream>>>(na_bias, ha_bias, wa_bias, AB);
  k_wt   <<<256, 256, 0, stream>>>(proj_w, WT);
  k_cwt  <<<6400, 256, 0, stream>>>(conv5_w, CWT);
  k_lka  <<<1024, 256, 0, stream>>>(x, lka_w, lka_b, Y);
  k_conv5<<<512, 256, 0, stream>>>(Y, CWT, conv5_b, V5);
  k_pool <<<128, 256, 0, stream>>>(Y, AT, ATK);
  k_cbam_a<<<128, 256, 0, stream>>>(V5, caa1_w, caa1_b, caa2_w, caa2_b,
                                    cam1_w, cam1_b, cam2_w, cam2_b, CHG);
  k_cbam_b<<<128, 256, 0, stream>>>(V5, CHG, sa_w, sa_b);
  k_attn <<<1024, 256, 0, stream>>>(Y, rpbt, X1S);
  k_cinter<<<128, 256, 0, stream>>>(X1S, ci1_w, ci1_b, bn_g, bn_b, ci2_w, ci2_b, CMAP);
  k_agentv<<<1024, 256, 0, stream>>>(Y, V5, AT, ATK, PBT, AGV);
  k_xo1  <<<1024, 128, 0, stream>>>(Y, AT, ATK, AB, AGV, XO);
  k_dwc  <<<1024, 256, 0, stream>>>(Y, CMAP, dwc_w, dwc_b, XO);
  k_proj <<<896, 256, 0, stream>>>(XO, WT, proj_b, out);
}

// Round 2
// 1465.575 us; speedup vs baseline: 1.4941x; 1.4941x over previous
//
#include <hip/hip_runtime.h>

// Problem constants
#define NB    128
#define NC    256
#define NPOS  196
#define NHEAD 8
#define NAG   49
#define YSTR  150528      // 768*196 per-batch y floats
#define VOFF  50176       // v_raw offset inside y (256*196)
#define QOFF  100352      // q_raw offset inside y (512*196)
#define SCL   0.17677669529663687f   // 32^-0.5

// Workspace layout (floats). Total = 38,885,440 floats = 155.5 MB.
#define WS_Y    0u
#define WS_V5   19267584u
#define WS_AT   25690112u
#define WS_ATK  27295744u
#define WS_CHG  28901376u
#define WS_CMAP 28934144u
#define WS_PBT  28966912u
#define WS_AB   29043744u
#define WS_X1S  29120576u
#define WS_AGV  29153344u
#define WS_XO   30758976u
#define WS_WT   37181504u
#define WS_CWT  37247040u   // now: Whi (1.6M ushort) + Wlo (1.6M ushort)

typedef __attribute__((ext_vector_type(8))) short short8;
typedef __attribute__((ext_vector_type(4))) float f32x4;
typedef unsigned short ushort_t;
typedef unsigned int uint_t;

__device__ __forceinline__ float sigmoidf_(float x){ return 1.0f/(1.0f+__expf(-x)); }

__device__ __forceinline__ ushort_t bf16hi(float x){
  uint_t u = __float_as_uint(x);
  uint_t r = (u + 0x7FFFu + ((u >> 16) & 1u)) >> 16;   // RNE
  return (ushort_t)r;
}

// bilinear upsample 7x7 -> 14x14 sample at (i,j), matching reference grid()
__device__ __forceinline__ float bilin7(const float* __restrict__ src, int i, int j){
  float pi = fmaxf(0.5f*(float)i - 0.25f, 0.f);
  int i0 = (int)pi; if (i0 > 6) i0 = 6;
  int i1 = i0 + 1;  if (i1 > 6) i1 = 6;
  float li = pi - (float)i0;
  float pj = fmaxf(0.5f*(float)j - 0.25f, 0.f);
  int j0 = (int)pj; if (j0 > 6) j0 = 6;
  int j1 = j0 + 1;  if (j1 > 6) j1 = 6;
  float lj = pj - (float)j0;
  float v00 = src[i0*7+j0], v01 = src[i0*7+j1];
  float v10 = src[i1*7+j0], v11 = src[i1*7+j1];
  float t0 = v00*(1.f-lj) + v01*lj;
  float t1 = v10*(1.f-lj) + v11*lj;
  return t0*(1.f-li) + t1*li;
}

// 5x5 conv over a zero-padded [18][20] plane, producing one 14-wide output row r.
__device__ __forceinline__ void conv5x5_row(const float* __restrict__ plane, int r,
                                            const float* __restrict__ w25, float* acc14){
  #pragma unroll
  for (int di = 0; di < 5; ++di){
    const float4* pr = (const float4*)(plane + (r+di)*20);
    float4 p0 = pr[0], p1 = pr[1], p2 = pr[2], p3 = pr[3], p4 = pr[4];
    float row[20] = {p0.x,p0.y,p0.z,p0.w, p1.x,p1.y,p1.z,p1.w, p2.x,p2.y,p2.z,p2.w,
                     p3.x,p3.y,p3.z,p3.w, p4.x,p4.y,p4.z,p4.w};
    #pragma unroll
    for (int dj = 0; dj < 5; ++dj){
      float w = w25[di*5+dj];
      #pragma unroll
      for (int j = 0; j < 14; ++j) acc14[j] = fmaf(row[j+dj], w, acc14[j]);
    }
  }
}

// ---------- prep kernels ----------
__global__ void k_pb(const float* __restrict__ an, const float* __restrict__ ah,
                     const float* __restrict__ aw, float* __restrict__ PBT){
  int t = blockIdx.x*256 + threadIdx.x;
  if (t >= NHEAD*NPOS*NAG) return;
  int a = t % NAG;
  int r = t / NAG;
  int n = r % NPOS;
  int h = r / NPOS;
  int i = n/14, j = n - (n/14)*14;
  float v = bilin7(an + ((size_t)h*NAG + a)*49, i, j);
  v += ah[((size_t)h*NAG + a)*14 + i] + aw[((size_t)h*NAG + a)*14 + j];
  PBT[t] = v;   // [h][n][a]
}

__global__ void k_ab(const float* __restrict__ na, const float* __restrict__ ha,
                     const float* __restrict__ wa, float* __restrict__ AB){
  int t = blockIdx.x*256 + threadIdx.x;
  if (t >= NHEAD*NPOS*NAG) return;
  int a = t % NAG;
  int r = t / NAG;
  int n = r % NPOS;
  int h = r / NPOS;
  int i = n/14, j = n - (n/14)*14;
  float v = bilin7(na + ((size_t)h*NAG + a)*49, i, j);
  v += ha[((size_t)h*14 + i)*NAG + a] + wa[((size_t)h*14 + j)*NAG + a];
  AB[t] = v;    // [h][n][a]
}

__global__ void k_wt(const float* __restrict__ pw, float* __restrict__ WT){
  int t = blockIdx.x*256 + threadIdx.x;
  if (t >= 65536) return;
  int k = t >> 8, c = t & 255;
  WT[t] = pw[c*256 + k];          // WT[k][c] = proj_w[c][k]
}

// conv5 weights -> bf16 hi/lo, layout [tap][co][ci]
__global__ void k_cw2(const float* __restrict__ cw, ushort_t* __restrict__ Whi,
                      ushort_t* __restrict__ Wlo){
  int t = blockIdx.x*256 + threadIdx.x;
  if (t >= 1638400) return;
  int ci = t & 255;
  int r  = t >> 8;                // tap*256 + co
  int co = r & 255;
  int tap = r >> 8;
  float w = cw[((size_t)co*256 + ci)*25 + tap];
  ushort_t h = bf16hi(w);
  Whi[t] = h;
  Wlo[t] = bf16hi(w - __uint_as_float(((uint_t)h) << 16));
}

// ---------- lka depthwise-ish conv (groups=256, 3 outputs per input channel) ----------
__global__ __launch_bounds__(256) void k_lka(const float* __restrict__ x, const float* __restrict__ lw,
                                             const float* __restrict__ lb, float* __restrict__ Y){
  int b = blockIdx.x >> 3, gb = blockIdx.x & 7;
  int g0 = gb*32;                               // input channels [g0,g0+32)
  __shared__ __align__(16) float pl[32*360];    // [ch][18*20] padded planes
  int tid = threadIdx.x;
  for (int t = tid; t < 32*360; t += 256) pl[t] = 0.f;
  __syncthreads();
  for (int t = tid; t < 32*196; t += 256){
    int gl = t & 31, s = t >> 5;
    int i = s/14, j = s - i*14;
    pl[gl*360 + (i+2)*20 + j + 2] = x[((size_t)b*196 + s)*256 + g0 + gl];
  }
  __syncthreads();
  for (int t = tid; t < 96*14; t += 256){
    int ocl = t/14, r = t - ocl*14;
    int o  = g0*3 + ocl;          // output channel; uses input channel o/3
    int gl = ocl/3;
    float w25[25];
    #pragma unroll
    for (int u = 0; u < 25; ++u) w25[u] = lw[o*25 + u];
    float acc[14];
    float bv = lb[o];
    #pragma unroll
    for (int j = 0; j < 14; ++j) acc[j] = bv;
    conv5x5_row(&pl[gl*360], r, w25, acc);
    float* dst = Y + ((size_t)b*768 + o)*196 + r*14;
    #pragma unroll
    for (int j = 0; j < 14; ++j) dst[j] = acc[j];
  }
}

// ---------- conv5 via split-bf16 MFMA ----------
// Per block: one batch, 64 output channels. GEMM C[s(256 pad)][co64] =
// sum over 25 taps x 8 ci-chunks(32) of P[s][ci] * W[ci][co], hi/lo split,
// 3 MFMA products (ahi*bhi + ahi*blo + alo*bhi); dropped alo*blo ~2^-18.
__global__ __launch_bounds__(256, 2) void k_conv5(const float* __restrict__ Y,
    const ushort_t* __restrict__ Whi, const ushort_t* __restrict__ Wlo,
    const float* __restrict__ cb, float* __restrict__ V5){
  int b = blockIdx.x >> 2, cog = blockIdx.x & 3;
  int co0 = cog*64;
  // padded plane, transposed: [plane_pos 360][ci 32] (+pad to 40 for banks)
  __shared__ __align__(16) ushort_t PtHi[360*40];
  __shared__ __align__(16) ushort_t PtLo[360*40];
  __shared__ __align__(16) ushort_t WsHi[64*40];   // [co 64][ci 32] (+pad)
  __shared__ __align__(16) ushort_t WsLo[64*40];
  int tid  = threadIdx.x;
  int lane = tid & 63, wv = tid >> 6;
  int mrow = lane & 15, quad = lane >> 4;

  for (int t = tid; t < 14400; t += 256){ PtHi[t] = 0; PtLo[t] = 0; }

  // per-lane A fragment base addresses (ushort index), one per m-tile
  int Ab[4];
  #pragma unroll
  for (int mt = 0; mt < 4; ++mt){
    int s = wv*64 + mt*16 + mrow;
    int p0 = 0;
    if (s < 196){ int i = s/14, j = s - i*14; p0 = i*20 + j; }
    Ab[mt] = p0*40 + quad*8;
  }
  int Bb = mrow*40 + quad*8;

  f32x4 acc[4][4];
  #pragma unroll
  for (int mt = 0; mt < 4; ++mt)
    #pragma unroll
    for (int nt = 0; nt < 4; ++nt) acc[mt][nt] = (f32x4){0.f,0.f,0.f,0.f};

  const float* src = Y + (size_t)b*YSTR + VOFF;   // v_raw [ci][s]
  #pragma unroll 1
  for (int cc = 0; cc < 8; ++cc){
    int ci0 = cc*32;
    __syncthreads();
    // stage A: 32 ci planes -> transposed padded bf16 hi/lo
    for (int idx = tid; idx < 6272; idx += 256){
      int ci = idx / 196, s = idx - ci*196;
      float v = src[ci0*196 + idx];
      ushort_t h = bf16hi(v);
      ushort_t l = bf16hi(v - __uint_as_float(((uint_t)h) << 16));
      int i = s/14, j = s - i*14;
      int p = (i+2)*20 + (j+2);
      PtHi[p*40 + ci] = h;
      PtLo[p*40 + ci] = l;
    }
    #pragma unroll 1
    for (int tap = 0; tap < 25; ++tap){
      if (tap) __syncthreads();
      // stage B: W[tap][co0..+64][ci0..+32] hi/lo
      {
        const uint_t* gh = (const uint_t*)(Whi + ((size_t)tap*256 + co0)*256 + ci0);
        const uint_t* gl = (const uint_t*)(Wlo + ((size_t)tap*256 + co0)*256 + ci0);
        uint_t* sh = (uint_t*)WsHi; uint_t* sl = (uint_t*)WsLo;
        for (int t = tid; t < 1024; t += 256){
          int co = t >> 4, cp = t & 15;
          sh[co*20 + cp] = gh[co*128 + cp];
          sl[co*20 + cp] = gl[co*128 + cp];
        }
      }
      __syncthreads();
      int toff = ((tap/5)*20 + (tap%5))*40;
      short8 ah[4], al[4], bh[4], bl[4];
      #pragma unroll
      for (int nt = 0; nt < 4; ++nt){
        bh[nt] = *(const short8*)&WsHi[Bb + nt*640];
        bl[nt] = *(const short8*)&WsLo[Bb + nt*640];
      }
      #pragma unroll
      for (int mt = 0; mt < 4; ++mt){
        ah[mt] = *(const short8*)&PtHi[Ab[mt] + toff];
        al[mt] = *(const short8*)&PtLo[Ab[mt] + toff];
      }
      #pragma unroll
      for (int mt = 0; mt < 4; ++mt)
        #pragma unroll
        for (int nt = 0; nt < 4; ++nt){
          acc[mt][nt] = __builtin_amdgcn_mfma_f32_16x16x32_bf16(ah[mt], bh[nt], acc[mt][nt], 0, 0, 0);
          acc[mt][nt] = __builtin_amdgcn_mfma_f32_16x16x32_bf16(ah[mt], bl[nt], acc[mt][nt], 0, 0, 0);
          acc[mt][nt] = __builtin_amdgcn_mfma_f32_16x16x32_bf16(al[mt], bh[nt], acc[mt][nt], 0, 0, 0);
        }
    }
  }
  // epilogue: bias + scatter into scrambled v5 layout
  float* vb = V5 + (size_t)b*50176;
  #pragma unroll
  for (int nt = 0; nt < 4; ++nt){
    int co = co0 + nt*16 + mrow;        // C/D col = lane&15
    float bv = cb[co];
    #pragma unroll
    for (int mt = 0; mt < 4; ++mt){
      #pragma unroll
      for (int r = 0; r < 4; ++r){
        int s = wv*64 + mt*16 + quad*4 + r;   // C/D row = (lane>>4)*4+reg
        if (s < 196){
          int f = co*196 + s;   // v5[b, f%256, f/256] = z[b, f]
          vb[(f & 255)*196 + (f >> 8)] = acc[mt][nt][r] + bv;
        }
      }
    }
  }
}

// ---------- agent token pooling: at = 2x2-mean of q_raw, atk = 2x2-max of k_raw ----------
__global__ __launch_bounds__(256) void k_pool(const float* __restrict__ Y, float* __restrict__ AT, float* __restrict__ ATK){
  int b = blockIdx.x; int c = threadIdx.x;
  const float* qp = Y + ((size_t)b*768 + 512 + c)*196;
  const float* kp = Y + ((size_t)b*768 + c)*196;
  for (int a = 0; a < 49; ++a){
    int p1 = a/7, p2 = a - p1*7;
    int s = p1*28 + p2*2;
    float q0 = qp[s], q1 = qp[s+1], q2 = qp[s+14], q3 = qp[s+15];
    AT[((size_t)b*49 + a)*256 + c] = 0.25f*(q0+q1+q2+q3);
    float k0 = kp[s], k1 = kp[s+1], k2 = kp[s+14], k3 = kp[s+15];
    ATK[((size_t)b*49 + a)*256 + c] = fmaxf(fmaxf(k0,k1), fmaxf(k2,k3));
  }
}

// ---------- cbam stage A: channel gate ----------
__global__ __launch_bounds__(256) void k_cbam_a(const float* __restrict__ V5,
    const float* __restrict__ caa1w, const float* __restrict__ caa1b,
    const float* __restrict__ caa2w, const float* __restrict__ caa2b,
    const float* __restrict__ cam1w, const float* __restrict__ cam1b,
    const float* __restrict__ cam2w, const float* __restrict__ cam2b,
    float* __restrict__ CHG){
  int b = blockIdx.x, c = threadIdx.x;
  __shared__ float avg[256], mx[256], t1[16], t2[16];
  const float* pp = V5 + ((size_t)b*256 + c)*196;
  float s = 0.f, m = -1e30f;
  for (int i = 0; i < 196; ++i){ float v = pp[i]; s += v; m = fmaxf(m, v); }
  avg[c] = s * (1.0f/196.0f); mx[c] = m;
  __syncthreads();
  if (c < 16){
    float a1 = caa1b[c], a2 = cam1b[c];
    #pragma unroll 4
    for (int k = 0; k < 256; ++k){
      a1 = fmaf(caa1w[(c*256 + k)*9 + 4], avg[k], a1);   // 3x3 center tap
      a2 = fmaf(cam1w[c*256 + k], mx[k], a2);            // 1x1
    }
    t1[c] = fmaxf(a1, 0.f);
    t2[c] = fmaxf(a2, 0.f);
  }
  __syncthreads();
  float y1 = caa2b[c], y2 = cam2b[c];
  #pragma unroll
  for (int k = 0; k < 16; ++k){
    y1 = fmaf(caa2w[(c*16 + k)*9 + 4], t1[k], y1);
    y2 = fmaf(cam2w[c*16 + k], t2[k], y2);
  }
  CHG[b*256 + c] = sigmoidf_(sigmoidf_(y1) + sigmoidf_(y2));
}

// ---------- cbam stage B: spatial mask (9x9 pad4 over [mean,max]) + in-place gate ----------
__global__ __launch_bounds__(256) void k_cbam_b(float* __restrict__ V5, const float* __restrict__ CHG,
    const float* __restrict__ saw, const float* __restrict__ sab){
  int b = blockIdx.x; int tid = threadIdx.x;
  __shared__ float chg[256];
  __shared__ float mp[22*22], xp[22*22];
  __shared__ float mk[196];
  chg[tid] = CHG[b*256 + tid];
  for (int t = tid; t < 484; t += 256){ mp[t] = 0.f; xp[t] = 0.f; }
  __syncthreads();
  if (tid < 196){
    int i = tid/14, j = tid - i*14;
    float s = 0.f, m = -1e30f;
    const float* vb = V5 + (size_t)b*256*196 + tid;
    for (int c = 0; c < 256; ++c){
      float v = chg[c] * vb[c*196];
      s += v; m = fmaxf(m, v);
    }
    mp[(i+4)*22 + j+4] = s*(1.f/256.f);
    xp[(i+4)*22 + j+4] = m;
  }
  __syncthreads();
  if (tid < 196){
    int i = tid/14, j = tid - i*14;
    float acc = sab[0];
    for (int di = 0; di < 9; ++di){
      #pragma unroll
      for (int dj = 0; dj < 9; ++dj){
        acc = fmaf(mp[(i+di)*22 + j+dj], saw[di*9+dj], acc);
        acc = fmaf(xp[(i+di)*22 + j+dj], saw[81 + di*9+dj], acc);
      }
    }
    mk[tid] = sigmoidf_(acc);
  }
  __syncthreads();
  if (tid < 196){
    float m = mk[tid];
    float* vb = V5 + (size_t)b*256*196 + tid;
    for (int c = 0; c < 256; ++c) vb[c*196] = chg[c]*vb[c*196]*m;
  }
}

// ---------- big NxN attention; only the per-(b,c) mean of x1 is needed downstream ----------
__global__ __launch_bounds__(256) void k_attn(const float* __restrict__ Y, const float* __restrict__ rpbt,
                                              float* __restrict__ X1S){
  int b = blockIdx.x >> 3, h = blockIdx.x & 7;
  __shared__ float rp[729];
  __shared__ float xs[196*33];
  int tid = threadIdx.x;
  for (int t = tid; t < 729; t += 256) rp[t] = rpbt[t*8 + h];
  __syncthreads();
  const float* yb = Y + (size_t)b*YSTR;
  if (tid < 196){
    int n = tid;
    float q[32];
    {
      const float4* q4 = (const float4*)(yb + QOFF + (size_t)n*256 + h*32);
      #pragma unroll
      for (int u = 0; u < 8; ++u){
        float4 v = q4[u];
        q[4*u] = v.x*SCL; q[4*u+1] = v.y*SCL; q[4*u+2] = v.z*SCL; q[4*u+3] = v.w*SCL;
      }
    }
    int ri = n/14, ci = n - ri*14;
    int bidx = (ri + 13)*27 + (ci + 13);
    float acc[32];
    #pragma unroll
    for (int d = 0; d < 32; ++d) acc[d] = 0.f;
    float l = 0.f;
    int rj = 0, cj = 0;
    for (int j = 0; j < 196; ++j){
      const float4* k4 = (const float4*)(yb + (size_t)j*256 + h*32);
      float s0 = 0.f, s1 = 0.f;
      #pragma unroll
      for (int u = 0; u < 8; u += 2){
        float4 a = k4[u], bb = k4[u+1];
        s0 = fmaf(q[4*u+0],a.x, fmaf(q[4*u+1],a.y, fmaf(q[4*u+2],a.z, fmaf(q[4*u+3],a.w, s0))));
        s1 = fmaf(q[4*u+4],bb.x, fmaf(q[4*u+5],bb.y, fmaf(q[4*u+6],bb.z, fmaf(q[4*u+7],bb.w, s1))));
      }
      float s = s0 + s1 + rp[bidx - rj*27 - cj];
      float p = __expf(s);       // logits are O(0.1): max-free softmax is safe
      l += p;
      const float4* v4 = (const float4*)(yb + VOFF + (size_t)j*256 + h*32);
      #pragma unroll
      for (int u = 0; u < 8; ++u){
        float4 vv = v4[u];
        acc[4*u]   = fmaf(p, vv.x, acc[4*u]);
        acc[4*u+1] = fmaf(p, vv.y, acc[4*u+1]);
        acc[4*u+2] = fmaf(p, vv.z, acc[4*u+2]);
        acc[4*u+3] = fmaf(p, vv.w, acc[4*u+3]);
      }
      if (++cj == 14){ cj = 0; ++rj; }
    }
    float inv = 1.f/l;
    #pragma unroll
    for (int d = 0; d < 32; ++d) xs[n*33 + d] = acc[d]*inv;
  }
  __syncthreads();
  if (tid < 32){
    float s = 0.f;
    for (int n = 0; n < 196; ++n) s += xs[n*33 + tid];
    X1S[(size_t)b*256 + h*32 + tid] = s*(1.f/196.f);   // mean over n of x1[b,:,c]
  }
}

// ---------- chan_inter on x1 mean -> sigmoid gate CMAP ----------
__global__ __launch_bounds__(256) void k_cinter(const float* __restrict__ X1S,
    const float* __restrict__ ci1w, const float* __restrict__ ci1b,
    const float* __restrict__ bng, const float* __restrict__ bnb,
    const float* __restrict__ ci2w, const float* __restrict__ ci2b, float* __restrict__ CMAP){
  int b = blockIdx.x, c = threadIdx.x;
  __shared__ float p[256], tt[16];
  p[c] = X1S[b*256 + c];
  __syncthreads();
  if (c < 16){
    float a = ci1b[c];
    #pragma unroll 4
    for (int k = 0; k < 256; ++k) a = fmaf(ci1w[(c*256+k)*25 + 12], p[k], a);  // 5x5 center
    const float invs = 0.9999950000375f;   // 1/sqrt(1+1e-5)
    tt[c] = fmaxf(fmaf(bng[c]*invs, a, bnb[c]), 0.f);
  }
  __syncthreads();
  float a = ci2b[c];
  #pragma unroll
  for (int k = 0; k < 16; ++k) a = fmaf(ci2w[(c*16+k)*25 + 12], tt[k], a);
  CMAP[b*256 + c] = sigmoidf_(a);
}

// ---------- agent_v = softmax(at*scale@K^T+pb)@V1 + softmax(atk*scale@Q^T+pb)@V ----------
__global__ __launch_bounds__(256) void k_agentv(const float* __restrict__ Y, const float* __restrict__ V5,
    const float* __restrict__ AT, const float* __restrict__ ATK,
    const float* __restrict__ PBT, float* __restrict__ AGV){
  int b = blockIdx.x >> 3, h = blockIdx.x & 7;
  __shared__ float S[196*53];
  __shared__ float part[4*64];
  int tid = threadIdx.x;
  int wv = tid >> 6, lane = tid & 63;
  const float* yb  = Y + (size_t)b*YSTR;
  const float* vcb = V5 + (size_t)b*256*196;
  float ar[32], akr[32];
  if (lane < 49){
    const float4* ap = (const float4*)(AT  + ((size_t)b*49 + lane)*256 + h*32);
    const float4* kp = (const float4*)(ATK + ((size_t)b*49 + lane)*256 + h*32);
    #pragma unroll
    for (int u = 0; u < 8; ++u){
      float4 a = ap[u], k = kp[u];
      ar[4*u]=a.x; ar[4*u+1]=a.y; ar[4*u+2]=a.z; ar[4*u+3]=a.w;
      akr[4*u]=k.x; akr[4*u+1]=k.y; akr[4*u+2]=k.z; akr[4*u+3]=k.w;
    }
  }
  float acc[8];
  #pragma unroll
  for (int d = 0; d < 8; ++d) acc[d] = 0.f;
  int d0 = wv*8;

  // ---- pass 0: agent_attn (ar . K)*scale + pb ; x V1 (vc) ----
  {
    float lsum = 0.f;
    if (lane < 49){
      for (int n = wv; n < 196; n += 4){
        const float4* r4 = (const float4*)(yb + (size_t)n*256 + h*32);
        float s = 0.f;
        #pragma unroll
        for (int u = 0; u < 8; ++u){
          float4 v = r4[u];
          s = fmaf(ar[4*u],v.x, fmaf(ar[4*u+1],v.y, fmaf(ar[4*u+2],v.z, fmaf(ar[4*u+3],v.w, s))));
        }
        s = fmaf(s, SCL, PBT[((size_t)h*196 + n)*49 + lane]);
        float e = __expf(s);
        S[n*53 + lane] = e;
        lsum += e;
      }
    }
    part[wv*64 + lane] = lsum;
    __syncthreads();
    if (lane < 49){
      float l = part[lane] + part[64+lane] + part[128+lane] + part[192+lane];
      float inv = 1.f/l;
      float a8[8];
      #pragma unroll
      for (int d = 0; d < 8; ++d) a8[d] = 0.f;
      const float* vp = vcb + (h*32 + d0)*196;
      for (int n = 0; n < 196; ++n){
        float pv = S[n*53 + lane];
        #pragma unroll
        for (int d = 0; d < 8; ++d) a8[d] = fmaf(pv, vp[d*196 + n], a8[d]);
      }
      #pragma unroll
      for (int d = 0; d < 8; ++d) acc[d] += inv*a8[d];
    }
    __syncthreads();
  }
  // ---- pass 1: agent_attn1 (akr . Q_raw)*scale^2 + pb ; x V (y) ----
  {
    float lsum = 0.f;
    if (lane < 49){
      for (int n = wv; n < 196; n += 4){
        const float4* r4 = (const float4*)(yb + QOFF + (size_t)n*256 + h*32);
        float s = 0.f;
        #pragma unroll
        for (int u = 0; u < 8; ++u){
          float4 v = r4[u];
          s = fmaf(akr[4*u],v.x, fmaf(akr[4*u+1],v.y, fmaf(akr[4*u+2],v.z, fmaf(akr[4*u+3],v.w, s))));
        }
        s = fmaf(s, 0.03125f, PBT[((size_t)h*196 + n)*49 + lane]);
        float e = __expf(s);
        S[n*53 + lane] = e;
        lsum += e;
      }
    }
    part[wv*64 + lane] = lsum;
    __syncthreads();
    if (lane < 49){
      float l = part[lane] + part[64+lane] + part[128+lane] + part[192+lane];
      float inv = 1.f/l;
      float a8[8];
      #pragma unroll
      for (int d = 0; d < 8; ++d) a8[d] = 0.f;
      for (int n = 0; n < 196; ++n){
        float pv = S[n*53 + lane];
        const float* vp = yb + VOFF + (size_t)n*256 + h*32 + d0;
        #pragma unroll
        for (int d = 0; d < 8; ++d) a8[d] = fmaf(pv, vp[d], a8[d]);
      }
      #pragma unroll
      for (int d = 0; d < 8; ++d) acc[d] += inv*a8[d];
    }
  }
  if (lane < 49){
    float* dst = AGV + (((size_t)(b*8 + h)*49) + lane)*32 + d0;
    #pragma unroll
    for (int d = 0; d < 8; ++d) dst[d] = acc[d];
  }
}

// ---------- xo1 = (softmax(q*scale@at^T+ab) + softmax(k*scale@atk^T+ab)) @ agent_v ----------
__global__ __launch_bounds__(128) void k_xo1(const float* __restrict__ Y,
    const float* __restrict__ AT, const float* __restrict__ ATK,
    const float* __restrict__ AB, const float* __restrict__ AGV, float* __restrict__ XO){
  int b = blockIdx.x >> 3, h = blockIdx.x & 7;
  __shared__ float Pq[98*53], Pk[98*53];
  __shared__ float sq[98], sk[98];
  int tid = threadIdx.x;
  int wv = tid >> 6, lane = tid & 63;
  const float* yb = Y + (size_t)b*YSTR;
  float ar[32], akr[32];
  if (lane < 49){
    const float4* ap = (const float4*)(AT  + ((size_t)b*49 + lane)*256 + h*32);
    const float4* kp = (const float4*)(ATK + ((size_t)b*49 + lane)*256 + h*32);
    #pragma unroll
    for (int u = 0; u < 8; ++u){
      float4 a = ap[u], k = kp[u];
      ar[4*u]=a.x; ar[4*u+1]=a.y; ar[4*u+2]=a.z; ar[4*u+3]=a.w;
      akr[4*u]=k.x; akr[4*u+1]=k.y; akr[4*u+2]=k.z; akr[4*u+3]=k.w;
    }
  }
  const float* agvb = AGV + (size_t)(b*8 + h)*49*32;
  for (int chunk = 0; chunk < 2; ++chunk){
    int n0 = chunk*98;
    // q-attn logits (q_raw . at)*scale^2 + ab
    for (int nn = wv; nn < 98; nn += 2){
      int n = n0 + nn;
      float e = 0.f;
      if (lane < 49){
        const float4* r4 = (const float4*)(yb + QOFF + (size_t)n*256 + h*32);
        float s = 0.f;
        #pragma unroll
        for (int u = 0; u < 8; ++u){
          float4 v = r4[u];
          s = fmaf(ar[4*u],v.x, fmaf(ar[4*u+1],v.y, fmaf(ar[4*u+2],v.z, fmaf(ar[4*u+3],v.w, s))));
        }
        s = fmaf(s, 0.03125f, AB[((size_t)h*196 + n)*49 + lane]);
        e = __expf(s);
        Pq[nn*53 + lane] = e;
      }
      float t = e;
      #pragma unroll
      for (int o = 32; o > 0; o >>= 1) t += __shfl_xor(t, o);
      if (lane == 0) sq[nn] = t;
    }
    // k-attn logits (k_raw . atk)*scale + ab
    for (int nn = wv; nn < 98; nn += 2){
      int n = n0 + nn;
      float e = 0.f;
      if (lane < 49){
        const float4* r4 = (const float4*)(yb + (size_t)n*256 + h*32);
        float s = 0.f;
        #pragma unroll
        for (int u = 0; u < 8; ++u){
          float4 v = r4[u];
          s = fmaf(akr[4*u],v.x, fmaf(akr[4*u+1],v.y, fmaf(akr[4*u+2],v.z, fmaf(akr[4*u+3],v.w, s))));
        }
        s = fmaf(s, SCL, AB[((size_t)h*196 + n)*49 + lane]);
        e = __expf(s);
        Pk[nn*53 + lane] = e;
      }
      float t = e;
      #pragma unroll
      for (int o = 32; o > 0; o >>= 1) t += __shfl_xor(t, o);
      if (lane == 0) sk[nn] = t;
    }
    __syncthreads();
    if (tid < 98){
      int n = n0 + tid;
      float invq = 1.f/sq[tid], invk = 1.f/sk[tid];
      float out[32];
      #pragma unroll
      for (int d = 0; d < 32; ++d) out[d] = 0.f;
      for (int a = 0; a < 49; ++a){
        float pv = Pq[tid*53 + a]*invq + Pk[tid*53 + a]*invk;
        const float4* g4 = (const float4*)(agvb + a*32);
        #pragma unroll
        for (int u = 0; u < 8; ++u){
          float4 gv = g4[u];
          out[4*u]   = fmaf(pv, gv.x, out[4*u]);
          out[4*u+1] = fmaf(pv, gv.y, out[4*u+1]);
          out[4*u+2] = fmaf(pv, gv.z, out[4*u+2]);
          out[4*u+3] = fmaf(pv, gv.w, out[4*u+3]);
        }
      }
      float* dst = XO + ((size_t)b*196 + n)*256 + h*32;
      #pragma unroll
      for (int d = 0; d < 32; ++d) dst[d] = out[d];
    }
    __syncthreads();
  }
}

// ---------- fused depthwise conv: dwc(conv_x2 + qc), bias 2*dwc_b, accumulated into XO ----------
__global__ __launch_bounds__(256) void k_dwc(const float* __restrict__ Y, const float* __restrict__ CMAP,
    const float* __restrict__ dw, const float* __restrict__ db, float* __restrict__ XO){
  int b = blockIdx.x >> 3, cg = blockIdx.x & 7;
  int c0 = cg*32;
  __shared__ __align__(16) float pl[32*360];
  int tid = threadIdx.x;
  for (int t = tid; t < 32*360; t += 256) pl[t] = 0.f;
  __syncthreads();
  const float* yq = Y + (size_t)b*YSTR + QOFF;
  for (int t = tid; t < 32*196; t += 256){
    int cl = t & 31, s = t >> 5;
    int c = c0 + cl;
    int G = s*256 + c;                 // head-major flat index for conv_x2's scramble
    int hh = G / 6272;
    int rem = G - hh*6272;
    int n = rem >> 5, d = rem & 31;
    float cx2 = CMAP[b*256 + c] * yq[n*256 + hh*32 + d];   // sigmoid(cmap)*qs
    float qc  = yq[G];                                     // qc collapses to identity gather
    float v = SCL*(cx2 + qc);
    int i = s/14, j = s - i*14;
    pl[cl*360 + (i+2)*20 + j + 2] = v;
  }
  __syncthreads();
  for (int t = tid; t < 32*14; t += 256){
    int cl = t/14, r = t - cl*14;
    int c = c0 + cl;
    float w25[25];
    #pragma unroll
    for (int u = 0; u < 25; ++u) w25[u] = dw[c*25 + u];
    float acc[14];
    float b2 = 2.f*db[c];
    #pragma unroll
    for (int j = 0; j < 14; ++j) acc[j] = b2;
    conv5x5_row(&pl[cl*360], r, w25, acc);
    float* dst = XO + ((size_t)b*196 + r*14)*256 + c;
    #pragma unroll
    for (int j = 0; j < 14; ++j) dst[j*256] += acc[j];
  }
}

// ---------- final projection: out = XO @ proj_w^T + proj_b ----------
__global__ __launch_bounds__(256) void k_proj(const float* __restrict__ XO, const float* __restrict__ WT,
    const float* __restrict__ pbias, float* __restrict__ OUT){
  int bb = blockIdx.x / 7, nt = blockIdx.x % 7;
  int n0 = nt*28;
  int c = threadIdx.x;
  const float* xb = XO + ((size_t)bb*196 + n0)*256;
  float acc[28];
  #pragma unroll
  for (int r = 0; r < 28; ++r) acc[r] = 0.f;
  for (int k = 0; k < 256; k += 4){
    float w0 = WT[(k+0)*256 + c];
    float w1 = WT[(k+1)*256 + c];
    float w2 = WT[(k+2)*256 + c];
    float w3 = WT[(k+3)*256 + c];
    #pragma unroll
    for (int r = 0; r < 28; ++r){
      float4 xv = *(const float4*)(xb + r*256 + k);   // uniform address -> scalar/L1 path
      acc[r] = fmaf(xv.x, w0, fmaf(xv.y, w1, fmaf(xv.z, w2, fmaf(xv.w, w3, acc[r]))));
    }
  }
  float bv = pbias[c];
  float* dst = OUT + ((size_t)bb*196 + n0)*256 + c;
  #pragma unroll
  for (int r = 0; r < 28; ++r) dst[r*256] = acc[r] + bv;
}

extern "C" void kernel_launch(void* const* d_in, const int* in_sizes, int n_in,
                              void* d_out, int out_size, void* d_ws, size_t ws_size,
                              hipStream_t stream){
  (void)in_sizes; (void)n_in; (void)out_size; (void)ws_size;
  const float* x       = (const float*)d_in[0];
  const float* lka_w   = (const float*)d_in[3];
  const float* lka_b   = (const float*)d_in[4];
  const float* conv5_w = (const float*)d_in[5];
  const float* conv5_b = (const float*)d_in[6];
  const float* caa1_w  = (const float*)d_in[7];
  const float* caa1_b  = (const float*)d_in[8];
  const float* caa2_w  = (const float*)d_in[9];
  const float* caa2_b  = (const float*)d_in[10];
  const float* cam1_w  = (const float*)d_in[11];
  const float* cam1_b  = (const float*)d_in[12];
  const float* cam2_w  = (const float*)d_in[13];
  const float* cam2_b  = (const float*)d_in[14];
  const float* sa_w    = (const float*)d_in[15];
  const float* sa_b    = (const float*)d_in[16];
  const float* ci1_w   = (const float*)d_in[17];
  const float* ci1_b   = (const float*)d_in[18];
  const float* bn_g    = (const float*)d_in[19];
  const float* bn_b    = (const float*)d_in[20];
  const float* ci2_w   = (const float*)d_in[21];
  const float* ci2_b   = (const float*)d_in[22];
  const float* rpbt    = (const float*)d_in[23];
  const float* an_bias = (const float*)d_in[24];
  const float* na_bias = (const float*)d_in[25];
  const float* ah_bias = (const float*)d_in[26];
  const float* aw_bias = (const float*)d_in[27];
  const float* ha_bias = (const float*)d_in[28];
  const float* wa_bias = (const float*)d_in[29];
  const float* dwc_w   = (const float*)d_in[30];
  const float* dwc_b   = (const float*)d_in[31];
  const float* proj_w  = (const float*)d_in[32];
  const float* proj_b  = (const float*)d_in[33];
  float* out = (float*)d_out;
  float* ws = (float*)d_ws;

  float* Y    = ws + WS_Y;
  float* V5   = ws + WS_V5;
  float* AT   = ws + WS_AT;
  float* ATK  = ws + WS_ATK;
  float* CHG  = ws + WS_CHG;
  float* CMAP = ws + WS_CMAP;
  float* PBT  = ws + WS_PBT;
  float* AB   = ws + WS_AB;
  float* X1S  = ws + WS_X1S;
  float* AGV  = ws + WS_AGV;
  float* XO   = ws + WS_XO;
  float* WT   = ws + WS_WT;
  ushort_t* Whi = (ushort_t*)(ws + WS_CWT);
  ushort_t* Wlo = Whi + 1638400;

  k_pb   <<<301, 256, 0, stream>>>(an_bias, ah_bias, aw_bias, PBT);
  k_ab   <<<301, 256, 0, stream>>>(na_bias, ha_bias, wa_bias, AB);
  k_wt   <<<256, 256, 0, stream>>>(proj_w, WT);
  k_cw2  <<<6400, 256, 0, stream>>>(conv5_w, Whi, Wlo);
  k_lka  <<<1024, 256, 0, stream>>>(x, lka_w, lka_b, Y);
  k_conv5<<<512, 256, 0, stream>>>(Y, Whi, Wlo, conv5_b, V5);
  k_pool <<<128, 256, 0, stream>>>(Y, AT, ATK);
  k_cbam_a<<<128, 256, 0, stream>>>(V5, caa1_w, caa1_b, caa2_w, caa2_b,
                                    cam1_w, cam1_b, cam2_w, cam2_b, CHG);
  k_cbam_b<<<128, 256, 0, stream>>>(V5, CHG, sa_w, sa_b);
  k_attn <<<1024, 256, 0, stream>>>(Y, rpbt, X1S);
  k_cinter<<<128, 256, 0, stream>>>(X1S, ci1_w, ci1_b, bn_g, bn_b, ci2_w, ci2_b, CMAP);
  k_agentv<<<1024, 256, 0, stream>>>(Y, V5, AT, ATK, PBT, AGV);
  k_xo1  <<<1024, 128, 0, stream>>>(Y, AT, ATK, AB, AGV, XO);
  k_dwc  <<<1024, 256, 0, stream>>>(Y, CMAP, dwc_w, dwc_b, XO);
  k_proj <<<896, 256, 0, stream>>>(XO, WT, proj_b, out);
}

// Round 3
// 1223.723 us; speedup vs baseline: 1.7894x; 1.1976x over previous
//
#include <hip/hip_runtime.h>

// Problem constants
#define NB    128
#define NC    256
#define NPOS  196
#define NHEAD 8
#define NAG   49
#define YSTR  150528      // 768*196 per-batch y floats
#define VOFF  50176       // v_raw offset inside y (256*196)
#define QOFF  100352      // q_raw offset inside y (512*196)
#define SCL   0.17677669529663687f   // 32^-0.5

// Workspace layout (floats). Total = 38,885,440 floats = 155.5 MB.
#define WS_Y    0u
#define WS_V5   19267584u
#define WS_AT   25690112u
#define WS_ATK  27295744u
#define WS_CHG  28901376u
#define WS_CMAP 28934144u
#define WS_PBT  28966912u
#define WS_AB   29043744u
#define WS_X1S  29120576u
#define WS_AGV  29153344u
#define WS_XO   30758976u
#define WS_WT   37181504u
#define WS_CWT  37247040u   // Wh: 1.6M ushort (fp16 conv5 weights, [tap][co][ci])

typedef __attribute__((ext_vector_type(8))) _Float16 half8;
typedef __attribute__((ext_vector_type(8))) short short8;
typedef __attribute__((ext_vector_type(4))) float f32x4;
typedef unsigned short ushort_t;
typedef unsigned int uint_t;

__device__ __forceinline__ float sigmoidf_(float x){ return 1.0f/(1.0f+__expf(-x)); }

// bilinear upsample 7x7 -> 14x14 sample at (i,j), matching reference grid()
__device__ __forceinline__ float bilin7(const float* __restrict__ src, int i, int j){
  float pi = fmaxf(0.5f*(float)i - 0.25f, 0.f);
  int i0 = (int)pi; if (i0 > 6) i0 = 6;
  int i1 = i0 + 1;  if (i1 > 6) i1 = 6;
  float li = pi - (float)i0;
  float pj = fmaxf(0.5f*(float)j - 0.25f, 0.f);
  int j0 = (int)pj; if (j0 > 6) j0 = 6;
  int j1 = j0 + 1;  if (j1 > 6) j1 = 6;
  float lj = pj - (float)j0;
  float v00 = src[i0*7+j0], v01 = src[i0*7+j1];
  float v10 = src[i1*7+j0], v11 = src[i1*7+j1];
  float t0 = v00*(1.f-lj) + v01*lj;
  float t1 = v10*(1.f-lj) + v11*lj;
  return t0*(1.f-li) + t1*li;
}

// 5x5 conv over a zero-padded [18][20] plane, producing one 14-wide output row r.
__device__ __forceinline__ void conv5x5_row(const float* __restrict__ plane, int r,
                                            const float* __restrict__ w25, float* acc14){
  #pragma unroll
  for (int di = 0; di < 5; ++di){
    const float4* pr = (const float4*)(plane + (r+di)*20);
    float4 p0 = pr[0], p1 = pr[1], p2 = pr[2], p3 = pr[3], p4 = pr[4];
    float row[20] = {p0.x,p0.y,p0.z,p0.w, p1.x,p1.y,p1.z,p1.w, p2.x,p2.y,p2.z,p2.w,
                     p3.x,p3.y,p3.z,p3.w, p4.x,p4.y,p4.z,p4.w};
    #pragma unroll
    for (int dj = 0; dj < 5; ++dj){
      float w = w25[di*5+dj];
      #pragma unroll
      for (int j = 0; j < 14; ++j) acc14[j] = fmaf(row[j+dj], w, acc14[j]);
    }
  }
}

// ---------- prep kernels ----------
__global__ void k_pb(const float* __restrict__ an, const float* __restrict__ ah,
                     const float* __restrict__ aw, float* __restrict__ PBT){
  int t = blockIdx.x*256 + threadIdx.x;
  if (t >= NHEAD*NPOS*NAG) return;
  int a = t % NAG;
  int r = t / NAG;
  int n = r % NPOS;
  int h = r / NPOS;
  int i = n/14, j = n - (n/14)*14;
  float v = bilin7(an + ((size_t)h*NAG + a)*49, i, j);
  v += ah[((size_t)h*NAG + a)*14 + i] + aw[((size_t)h*NAG + a)*14 + j];
  PBT[t] = v;   // [h][n][a]
}

__global__ void k_ab(const float* __restrict__ na, const float* __restrict__ ha,
                     const float* __restrict__ wa, float* __restrict__ AB){
  int t = blockIdx.x*256 + threadIdx.x;
  if (t >= NHEAD*NPOS*NAG) return;
  int a = t % NAG;
  int r = t / NAG;
  int n = r % NPOS;
  int h = r / NPOS;
  int i = n/14, j = n - (n/14)*14;
  float v = bilin7(na + ((size_t)h*NAG + a)*49, i, j);
  v += ha[((size_t)h*14 + i)*NAG + a] + wa[((size_t)h*14 + j)*NAG + a];
  AB[t] = v;    // [h][n][a]
}

__global__ void k_wt(const float* __restrict__ pw, float* __restrict__ WT){
  int t = blockIdx.x*256 + threadIdx.x;
  if (t >= 65536) return;
  int k = t >> 8, c = t & 255;
  WT[t] = pw[c*256 + k];          // WT[k][c] = proj_w[c][k]
}

// conv5 weights -> fp16, layout [tap][co][ci]
__global__ void k_cw2(const float* __restrict__ cw, ushort_t* __restrict__ Wh){
  int t = blockIdx.x*256 + threadIdx.x;
  if (t >= 1638400) return;
  int ci = t & 255;
  int r  = t >> 8;
  int co = r & 255;
  int tap = r >> 8;
  _Float16 h = (_Float16)cw[((size_t)co*256 + ci)*25 + tap];
  Wh[t] = __builtin_bit_cast(ushort_t, h);
}

// ---------- lka depthwise-ish conv (groups=256, 3 outputs per input channel) ----------
__global__ __launch_bounds__(256) void k_lka(const float* __restrict__ x, const float* __restrict__ lw,
                                             const float* __restrict__ lb, float* __restrict__ Y){
  int b = blockIdx.x >> 3, gb = blockIdx.x & 7;
  int g0 = gb*32;                               // input channels [g0,g0+32)
  __shared__ __align__(16) float pl[32*360];    // [ch][18*20] padded planes
  int tid = threadIdx.x;
  for (int t = tid; t < 32*360; t += 256) pl[t] = 0.f;
  __syncthreads();
  for (int t = tid; t < 32*196; t += 256){
    int gl = t & 31, s = t >> 5;
    int i = s/14, j = s - i*14;
    pl[gl*360 + (i+2)*20 + j + 2] = x[((size_t)b*196 + s)*256 + g0 + gl];
  }
  __syncthreads();
  for (int t = tid; t < 96*14; t += 256){
    int ocl = t/14, r = t - ocl*14;
    int o  = g0*3 + ocl;          // output channel; uses input channel o/3
    int gl = ocl/3;
    float w25[25];
    #pragma unroll
    for (int u = 0; u < 25; ++u) w25[u] = lw[o*25 + u];
    float acc[14];
    float bv = lb[o];
    #pragma unroll
    for (int j = 0; j < 14; ++j) acc[j] = bv;
    conv5x5_row(&pl[gl*360], r, w25, acc);
    float* dst = Y + ((size_t)b*768 + o)*196 + r*14;
    #pragma unroll
    for (int j = 0; j < 14; ++j) dst[j] = acc[j];
  }
}

// ---------- conv5 via fp16 MFMA implicit GEMM ----------
// Per block: one batch, 64 output channels. C[s(256 pad)][co64] =
// sum over 25 taps x 8 ci-chunks(32) of P[s][ci] * W[ci][co], all fp16
// inputs (error ~3e-4 max, under 1.9e-3 threshold), f32 accumulate.
// LDS layouts use a quad XOR-swizzle so all b128 fragment reads are <=2-way.
__global__ __launch_bounds__(256, 2) void k_conv5(const float* __restrict__ Y,
    const ushort_t* __restrict__ Wh, const float* __restrict__ cb, float* __restrict__ V5){
  int b = blockIdx.x >> 2, cog = blockIdx.x & 3;
  int co0 = cog*64;
  __shared__ __align__(16) ushort_t Pt[360*40];     // fp16 A: [pos][ci32 swizzled]
  __shared__ __align__(16) ushort_t Wsm[5*64*40];   // fp16 B: [tap-of-row][co][ci32 swizzled]
  __shared__ float T[32*200];                       // epilogue transpose
  int tid  = threadIdx.x;
  int lane = tid & 63, wv = tid >> 6;
  int mrow = lane & 15, quad = lane >> 4;

  // zero-fill Pt once; borders stay zero across chunks
  for (int t = tid; t < 7200; t += 256) ((uint_t*)Pt)[t] = 0;

  // per-lane A plane-row base per m-tile (unpadded base; taps add di*20+dj)
  int prow[4];
  #pragma unroll
  for (int mt = 0; mt < 4; ++mt){
    int s = wv*64 + mt*16 + mrow;
    int p0 = 0;
    if (s < 196){ int i = s/14, j = s - i*14; p0 = i*20 + j; }
    prow[mt] = p0;
  }

  f32x4 acc[4][4];
  #pragma unroll
  for (int mt = 0; mt < 4; ++mt)
    #pragma unroll
    for (int nt = 0; nt < 4; ++nt) acc[mt][nt] = (f32x4){0.f,0.f,0.f,0.f};

  const float* src = Y + (size_t)b*YSTR + VOFF;   // v_raw [ci][s]
  int wco = tid >> 2, wpart = tid & 3;            // W-staging roles

  #pragma unroll 1
  for (int cc = 0; cc < 8; ++cc){
    __syncthreads();
    // stage A: 32 ci planes -> fp16 swizzled [pos][ci]
    if (tid < 196){
      int s = tid; int i = s/14, j = s - i*14;
      int p = (i+2)*20 + (j+2);
      const float* s0 = src + (cc*32)*196 + s;
      #pragma unroll
      for (int cp = 0; cp < 16; ++cp){
        float v0 = s0[(2*cp)*196];
        float v1 = s0[(2*cp+1)*196];
        _Float16 h0 = (_Float16)v0, h1 = (_Float16)v1;
        uint_t pk = (uint_t)__builtin_bit_cast(ushort_t, h0)
                  | ((uint_t)__builtin_bit_cast(ushort_t, h1) << 16);
        int q = cp >> 2;
        *(uint_t*)&Pt[p*40 + (((q ^ p) & 3) << 3) + ((2*cp) & 7)] = pk;
      }
    }
    #pragma unroll 1
    for (int di = 0; di < 5; ++di){
      __syncthreads();      // Wsm free to overwrite; also fences A writes (di=0)
      // stage W: taps di*5..di*5+4, 64 co x 32 ci fp16 each
      #pragma unroll
      for (int tp = 0; tp < 5; ++tp){
        int tap = di*5 + tp;
        const short8 g = *(const short8*)(Wh + ((size_t)tap*256 + co0 + wco)*256 + cc*32 + wpart*8);
        *(short8*)&Wsm[(tp*64 + wco)*40 + (((wpart ^ wco) & 3) << 3)] = g;
      }
      __syncthreads();
      #pragma unroll
      for (int dj = 0; dj < 5; ++dj){
        half8 a[4], bb[4];
        #pragma unroll
        for (int nt = 0; nt < 4; ++nt){
          int co = nt*16 + mrow;
          bb[nt] = *(const half8*)&Wsm[(dj*64 + co)*40 + (((quad ^ co) & 3) << 3)];
        }
        #pragma unroll
        for (int mt = 0; mt < 4; ++mt){
          int p = prow[mt] + di*20 + dj;
          a[mt] = *(const half8*)&Pt[p*40 + (((quad ^ p) & 3) << 3)];
        }
        #pragma unroll
        for (int mt = 0; mt < 4; ++mt)
          #pragma unroll
          for (int nt = 0; nt < 4; ++nt)
            acc[mt][nt] = __builtin_amdgcn_mfma_f32_16x16x32_f16(a[mt], bb[nt], acc[mt][nt], 0, 0, 0);
      }
    }
  }

  // epilogue: transpose through LDS, then coalesced stores into scrambled v5
  // v5 linear g = c*196 + p  <->  conv-output flat f = co*196 + s via
  // g = (f mod 256)*196 + f/256; per block g covers [co0*196, (co0+64)*196).
  float* vb = V5 + (size_t)b*50176 + co0*196;
  #pragma unroll
  for (int hf = 0; hf < 2; ++hf){
    __syncthreads();
    #pragma unroll
    for (int ntl = 0; ntl < 2; ++ntl){
      int nt = hf*2 + ntl;
      int col = ntl*16 + mrow;            // co local within half (0..31)
      #pragma unroll
      for (int mt = 0; mt < 4; ++mt){
        int sbase = wv*64 + mt*16 + quad*4;
        #pragma unroll
        for (int r = 0; r < 4; ++r){
          int s = sbase + r;
          if (s < 196) T[col*200 + s] = acc[mt][nt][r];
        }
      }
    }
    __syncthreads();
    for (int t = tid; t < 6272; t += 256){
      int cl = t / 196;                   // co local 0..31
      // out flat f = (co0+hf*32+cl)*196 + (t - cl*196); scatter index:
      int f = (co0 + hf*32)*196 + t;
      float val = T[t + cl*4] + cb[co0 + hf*32 + cl];
      // g-local within batch = (f&255)*196 + (f>>8); but f-range of this
      // block maps to a contiguous g window only per (f&255) stripe, so
      // store via the scramble directly — still mostly coalesced since
      // consecutive t with same cl advance f by 1 -> g jumps 196. Instead
      // store linear in f-space is wrong; use exact mapping:
      V5[(size_t)b*50176 + (size_t)(f & 255)*196 + (f >> 8)] = val;
    }
  }
  (void)vb;
}

// ---------- agent token pooling: at = 2x2-mean of q_raw, atk = 2x2-max of k_raw ----------
__global__ __launch_bounds__(256) void k_pool(const float* __restrict__ Y, float* __restrict__ AT, float* __restrict__ ATK){
  int b = blockIdx.x; int c = threadIdx.x;
  const float* qp = Y + ((size_t)b*768 + 512 + c)*196;
  const float* kp = Y + ((size_t)b*768 + c)*196;
  for (int a = 0; a < 49; ++a){
    int p1 = a/7, p2 = a - p1*7;
    int s = p1*28 + p2*2;
    float q0 = qp[s], q1 = qp[s+1], q2 = qp[s+14], q3 = qp[s+15];
    AT[((size_t)b*49 + a)*256 + c] = 0.25f*(q0+q1+q2+q3);
    float k0 = kp[s], k1 = kp[s+1], k2 = kp[s+14], k3 = kp[s+15];
    ATK[((size_t)b*49 + a)*256 + c] = fmaxf(fmaxf(k0,k1), fmaxf(k2,k3));
  }
}

// ---------- cbam stage A: channel gate ----------
__global__ __launch_bounds__(256) void k_cbam_a(const float* __restrict__ V5,
    const float* __restrict__ caa1w, const float* __restrict__ caa1b,
    const float* __restrict__ caa2w, const float* __restrict__ caa2b,
    const float* __restrict__ cam1w, const float* __restrict__ cam1b,
    const float* __restrict__ cam2w, const float* __restrict__ cam2b,
    float* __restrict__ CHG){
  int b = blockIdx.x, c = threadIdx.x;
  __shared__ float avg[256], mx[256], t1[16], t2[16];
  const float* pp = V5 + ((size_t)b*256 + c)*196;
  float s = 0.f, m = -1e30f;
  for (int i = 0; i < 196; ++i){ float v = pp[i]; s += v; m = fmaxf(m, v); }
  avg[c] = s * (1.0f/196.0f); mx[c] = m;
  __syncthreads();
  if (c < 16){
    float a1 = caa1b[c], a2 = cam1b[c];
    #pragma unroll 4
    for (int k = 0; k < 256; ++k){
      a1 = fmaf(caa1w[(c*256 + k)*9 + 4], avg[k], a1);   // 3x3 center tap
      a2 = fmaf(cam1w[c*256 + k], mx[k], a2);            // 1x1
    }
    t1[c] = fmaxf(a1, 0.f);
    t2[c] = fmaxf(a2, 0.f);
  }
  __syncthreads();
  float y1 = caa2b[c], y2 = cam2b[c];
  #pragma unroll
  for (int k = 0; k < 16; ++k){
    y1 = fmaf(caa2w[(c*16 + k)*9 + 4], t1[k], y1);
    y2 = fmaf(cam2w[c*16 + k], t2[k], y2);
  }
  CHG[b*256 + c] = sigmoidf_(sigmoidf_(y1) + sigmoidf_(y2));
}

// ---------- cbam stage B: spatial mask (9x9 pad4 over [mean,max]) + in-place gate ----------
__global__ __launch_bounds__(256) void k_cbam_b(float* __restrict__ V5, const float* __restrict__ CHG,
    const float* __restrict__ saw, const float* __restrict__ sab){
  int b = blockIdx.x; int tid = threadIdx.x;
  __shared__ float chg[256];
  __shared__ float mp[22*22], xp[22*22];
  __shared__ float mk[196];
  chg[tid] = CHG[b*256 + tid];
  for (int t = tid; t < 484; t += 256){ mp[t] = 0.f; xp[t] = 0.f; }
  __syncthreads();
  if (tid < 196){
    int i = tid/14, j = tid - i*14;
    float s = 0.f, m = -1e30f;
    const float* vb = V5 + (size_t)b*256*196 + tid;
    for (int c = 0; c < 256; ++c){
      float v = chg[c] * vb[c*196];
      s += v; m = fmaxf(m, v);
    }
    mp[(i+4)*22 + j+4] = s*(1.f/256.f);
    xp[(i+4)*22 + j+4] = m;
  }
  __syncthreads();
  if (tid < 196){
    int i = tid/14, j = tid - i*14;
    float acc = sab[0];
    for (int di = 0; di < 9; ++di){
      #pragma unroll
      for (int dj = 0; dj < 9; ++dj){
        acc = fmaf(mp[(i+di)*22 + j+dj], saw[di*9+dj], acc);
        acc = fmaf(xp[(i+di)*22 + j+dj], saw[81 + di*9+dj], acc);
      }
    }
    mk[tid] = sigmoidf_(acc);
  }
  __syncthreads();
  if (tid < 196){
    float m = mk[tid];
    float* vb = V5 + (size_t)b*256*196 + tid;
    for (int c = 0; c < 256; ++c) vb[c*196] = chg[c]*vb[c*196]*m;
  }
}

// ---------- big NxN attention; only the per-(b,c) mean of x1 is needed downstream ----------
__global__ __launch_bounds__(256) void k_attn(const float* __restrict__ Y, const float* __restrict__ rpbt,
                                              float* __restrict__ X1S){
  int b = blockIdx.x >> 3, h = blockIdx.x & 7;
  __shared__ float rp[729];
  __shared__ float xs[196*33];
  int tid = threadIdx.x;
  for (int t = tid; t < 729; t += 256) rp[t] = rpbt[t*8 + h];
  __syncthreads();
  const float* yb = Y + (size_t)b*YSTR;
  if (tid < 196){
    int n = tid;
    float q[32];
    {
      const float4* q4 = (const float4*)(yb + QOFF + (size_t)n*256 + h*32);
      #pragma unroll
      for (int u = 0; u < 8; ++u){
        float4 v = q4[u];
        q[4*u] = v.x*SCL; q[4*u+1] = v.y*SCL; q[4*u+2] = v.z*SCL; q[4*u+3] = v.w*SCL;
      }
    }
    int ri = n/14, ci = n - ri*14;
    int bidx = (ri + 13)*27 + (ci + 13);
    float acc[32];
    #pragma unroll
    for (int d = 0; d < 32; ++d) acc[d] = 0.f;
    float l = 0.f;
    int rj = 0, cj = 0;
    for (int j = 0; j < 196; ++j){
      const float4* k4 = (const float4*)(yb + (size_t)j*256 + h*32);
      float s0 = 0.f, s1 = 0.f;
      #pragma unroll
      for (int u = 0; u < 8; u += 2){
        float4 a = k4[u], bb = k4[u+1];
        s0 = fmaf(q[4*u+0],a.x, fmaf(q[4*u+1],a.y, fmaf(q[4*u+2],a.z, fmaf(q[4*u+3],a.w, s0))));
        s1 = fmaf(q[4*u+4],bb.x, fmaf(q[4*u+5],bb.y, fmaf(q[4*u+6],bb.z, fmaf(q[4*u+7],bb.w, s1))));
      }
      float s = s0 + s1 + rp[bidx - rj*27 - cj];
      float p = __expf(s);       // logits are O(0.1): max-free softmax is safe
      l += p;
      const float4* v4 = (const float4*)(yb + VOFF + (size_t)j*256 + h*32);
      #pragma unroll
      for (int u = 0; u < 8; ++u){
        float4 vv = v4[u];
        acc[4*u]   = fmaf(p, vv.x, acc[4*u]);
        acc[4*u+1] = fmaf(p, vv.y, acc[4*u+1]);
        acc[4*u+2] = fmaf(p, vv.z, acc[4*u+2]);
        acc[4*u+3] = fmaf(p, vv.w, acc[4*u+3]);
      }
      if (++cj == 14){ cj = 0; ++rj; }
    }
    float inv = 1.f/l;
    #pragma unroll
    for (int d = 0; d < 32; ++d) xs[n*33 + d] = acc[d]*inv;
  }
  __syncthreads();
  if (tid < 32){
    float s = 0.f;
    for (int n = 0; n < 196; ++n) s += xs[n*33 + tid];
    X1S[(size_t)b*256 + h*32 + tid] = s*(1.f/196.f);   // mean over n of x1[b,:,c]
  }
}

// ---------- chan_inter on x1 mean -> sigmoid gate CMAP ----------
__global__ __launch_bounds__(256) void k_cinter(const float* __restrict__ X1S,
    const float* __restrict__ ci1w, const float* __restrict__ ci1b,
    const float* __restrict__ bng, const float* __restrict__ bnb,
    const float* __restrict__ ci2w, const float* __restrict__ ci2b, float* __restrict__ CMAP){
  int b = blockIdx.x, c = threadIdx.x;
  __shared__ float p[256], tt[16];
  p[c] = X1S[b*256 + c];
  __syncthreads();
  if (c < 16){
    float a = ci1b[c];
    #pragma unroll 4
    for (int k = 0; k < 256; ++k) a = fmaf(ci1w[(c*256+k)*25 + 12], p[k], a);  // 5x5 center
    const float invs = 0.9999950000375f;   // 1/sqrt(1+1e-5)
    tt[c] = fmaxf(fmaf(bng[c]*invs, a, bnb[c]), 0.f);
  }
  __syncthreads();
  float a = ci2b[c];
  #pragma unroll
  for (int k = 0; k < 16; ++k) a = fmaf(ci2w[(c*16+k)*25 + 12], tt[k], a);
  CMAP[b*256 + c] = sigmoidf_(a);
}

// ---------- agent_v = softmax(at*scale@K^T+pb)@V1 + softmax(atk*scale@Q^T+pb)@V ----------
__global__ __launch_bounds__(256) void k_agentv(const float* __restrict__ Y, const float* __restrict__ V5,
    const float* __restrict__ AT, const float* __restrict__ ATK,
    const float* __restrict__ PBT, float* __restrict__ AGV){
  int b = blockIdx.x >> 3, h = blockIdx.x & 7;
  __shared__ float S[196*53];
  __shared__ float part[4*64];
  int tid = threadIdx.x;
  int wv = tid >> 6, lane = tid & 63;
  const float* yb  = Y + (size_t)b*YSTR;
  const float* vcb = V5 + (size_t)b*256*196;
  float ar[32], akr[32];
  if (lane < 49){
    const float4* ap = (const float4*)(AT  + ((size_t)b*49 + lane)*256 + h*32);
    const float4* kp = (const float4*)(ATK + ((size_t)b*49 + lane)*256 + h*32);
    #pragma unroll
    for (int u = 0; u < 8; ++u){
      float4 a = ap[u], k = kp[u];
      ar[4*u]=a.x; ar[4*u+1]=a.y; ar[4*u+2]=a.z; ar[4*u+3]=a.w;
      akr[4*u]=k.x; akr[4*u+1]=k.y; akr[4*u+2]=k.z; akr[4*u+3]=k.w;
    }
  }
  float acc[8];
  #pragma unroll
  for (int d = 0; d < 8; ++d) acc[d] = 0.f;
  int d0 = wv*8;

  // ---- pass 0: agent_attn (ar . K)*scale + pb ; x V1 (vc) ----
  {
    float lsum = 0.f;
    if (lane < 49){
      for (int n = wv; n < 196; n += 4){
        const float4* r4 = (const float4*)(yb + (size_t)n*256 + h*32);
        float s = 0.f;
        #pragma unroll
        for (int u = 0; u < 8; ++u){
          float4 v = r4[u];
          s = fmaf(ar[4*u],v.x, fmaf(ar[4*u+1],v.y, fmaf(ar[4*u+2],v.z, fmaf(ar[4*u+3],v.w, s))));
        }
        s = fmaf(s, SCL, PBT[((size_t)h*196 + n)*49 + lane]);
        float e = __expf(s);
        S[n*53 + lane] = e;
        lsum += e;
      }
    }
    part[wv*64 + lane] = lsum;
    __syncthreads();
    if (lane < 49){
      float l = part[lane] + part[64+lane] + part[128+lane] + part[192+lane];
      float inv = 1.f/l;
      float a8[8];
      #pragma unroll
      for (int d = 0; d < 8; ++d) a8[d] = 0.f;
      const float* vp = vcb + (h*32 + d0)*196;
      for (int n = 0; n < 196; ++n){
        float pv = S[n*53 + lane];
        #pragma unroll
        for (int d = 0; d < 8; ++d) a8[d] = fmaf(pv, vp[d*196 + n], a8[d]);
      }
      #pragma unroll
      for (int d = 0; d < 8; ++d) acc[d] += inv*a8[d];
    }
    __syncthreads();
  }
  // ---- pass 1: agent_attn1 (akr . Q_raw)*scale^2 + pb ; x V (y) ----
  {
    float lsum = 0.f;
    if (lane < 49){
      for (int n = wv; n < 196; n += 4){
        const float4* r4 = (const float4*)(yb + QOFF + (size_t)n*256 + h*32);
        float s = 0.f;
        #pragma unroll
        for (int u = 0; u < 8; ++u){
          float4 v = r4[u];
          s = fmaf(akr[4*u],v.x, fmaf(akr[4*u+1],v.y, fmaf(akr[4*u+2],v.z, fmaf(akr[4*u+3],v.w, s))));
        }
        s = fmaf(s, 0.03125f, PBT[((size_t)h*196 + n)*49 + lane]);
        float e = __expf(s);
        S[n*53 + lane] = e;
        lsum += e;
      }
    }
    part[wv*64 + lane] = lsum;
    __syncthreads();
    if (lane < 49){
      float l = part[lane] + part[64+lane] + part[128+lane] + part[192+lane];
      float inv = 1.f/l;
      float a8[8];
      #pragma unroll
      for (int d = 0; d < 8; ++d) a8[d] = 0.f;
      for (int n = 0; n < 196; ++n){
        float pv = S[n*53 + lane];
        const float* vp = yb + VOFF + (size_t)n*256 + h*32 + d0;
        #pragma unroll
        for (int d = 0; d < 8; ++d) a8[d] = fmaf(pv, vp[d], a8[d]);
      }
      #pragma unroll
      for (int d = 0; d < 8; ++d) acc[d] += inv*a8[d];
    }
  }
  if (lane < 49){
    float* dst = AGV + (((size_t)(b*8 + h)*49) + lane)*32 + d0;
    #pragma unroll
    for (int d = 0; d < 8; ++d) dst[d] = acc[d];
  }
}

// ---------- xo1 = (softmax(q*scale@at^T+ab) + softmax(k*scale@atk^T+ab)) @ agent_v ----------
__global__ __launch_bounds__(128) void k_xo1(const float* __restrict__ Y,
    const float* __restrict__ AT, const float* __restrict__ ATK,
    const float* __restrict__ AB, const float* __restrict__ AGV, float* __restrict__ XO){
  int b = blockIdx.x >> 3, h = blockIdx.x & 7;
  __shared__ float Pq[98*53], Pk[98*53];
  __shared__ float sq[98], sk[98];
  int tid = threadIdx.x;
  int wv = tid >> 6, lane = tid & 63;
  const float* yb = Y + (size_t)b*YSTR;
  float ar[32], akr[32];
  if (lane < 49){
    const float4* ap = (const float4*)(AT  + ((size_t)b*49 + lane)*256 + h*32);
    const float4* kp = (const float4*)(ATK + ((size_t)b*49 + lane)*256 + h*32);
    #pragma unroll
    for (int u = 0; u < 8; ++u){
      float4 a = ap[u], k = kp[u];
      ar[4*u]=a.x; ar[4*u+1]=a.y; ar[4*u+2]=a.z; ar[4*u+3]=a.w;
      akr[4*u]=k.x; akr[4*u+1]=k.y; akr[4*u+2]=k.z; akr[4*u+3]=k.w;
    }
  }
  const float* agvb = AGV + (size_t)(b*8 + h)*49*32;
  for (int chunk = 0; chunk < 2; ++chunk){
    int n0 = chunk*98;
    // q-attn logits (q_raw . at)*scale^2 + ab
    for (int nn = wv; nn < 98; nn += 2){
      int n = n0 + nn;
      float e = 0.f;
      if (lane < 49){
        const float4* r4 = (const float4*)(yb + QOFF + (size_t)n*256 + h*32);
        float s = 0.f;
        #pragma unroll
        for (int u = 0; u < 8; ++u){
          float4 v = r4[u];
          s = fmaf(ar[4*u],v.x, fmaf(ar[4*u+1],v.y, fmaf(ar[4*u+2],v.z, fmaf(ar[4*u+3],v.w, s))));
        }
        s = fmaf(s, 0.03125f, AB[((size_t)h*196 + n)*49 + lane]);
        e = __expf(s);
        Pq[nn*53 + lane] = e;
      }
      float t = e;
      #pragma unroll
      for (int o = 32; o > 0; o >>= 1) t += __shfl_xor(t, o);
      if (lane == 0) sq[nn] = t;
    }
    // k-attn logits (k_raw . atk)*scale + ab
    for (int nn = wv; nn < 98; nn += 2){
      int n = n0 + nn;
      float e = 0.f;
      if (lane < 49){
        const float4* r4 = (const float4*)(yb + (size_t)n*256 + h*32);
        float s = 0.f;
        #pragma unroll
        for (int u = 0; u < 8; ++u){
          float4 v = r4[u];
          s = fmaf(akr[4*u],v.x, fmaf(akr[4*u+1],v.y, fmaf(akr[4*u+2],v.z, fmaf(akr[4*u+3],v.w, s))));
        }
        s = fmaf(s, SCL, AB[((size_t)h*196 + n)*49 + lane]);
        e = __expf(s);
        Pk[nn*53 + lane] = e;
      }
      float t = e;
      #pragma unroll
      for (int o = 32; o > 0; o >>= 1) t += __shfl_xor(t, o);
      if (lane == 0) sk[nn] = t;
    }
    __syncthreads();
    if (tid < 98){
      int n = n0 + tid;
      float invq = 1.f/sq[tid], invk = 1.f/sk[tid];
      float out[32];
      #pragma unroll
      for (int d = 0; d < 32; ++d) out[d] = 0.f;
      for (int a = 0; a < 49; ++a){
        float pv = Pq[tid*53 + a]*invq + Pk[tid*53 + a]*invk;
        const float4* g4 = (const float4*)(agvb + a*32);
        #pragma unroll
        for (int u = 0; u < 8; ++u){
          float4 gv = g4[u];
          out[4*u]   = fmaf(pv, gv.x, out[4*u]);
          out[4*u+1] = fmaf(pv, gv.y, out[4*u+1]);
          out[4*u+2] = fmaf(pv, gv.z, out[4*u+2]);
          out[4*u+3] = fmaf(pv, gv.w, out[4*u+3]);
        }
      }
      float* dst = XO + ((size_t)b*196 + n)*256 + h*32;
      #pragma unroll
      for (int d = 0; d < 32; ++d) dst[d] = out[d];
    }
    __syncthreads();
  }
}

// ---------- fused depthwise conv: dwc(conv_x2 + qc), bias 2*dwc_b, accumulated into XO ----------
__global__ __launch_bounds__(256) void k_dwc(const float* __restrict__ Y, const float* __restrict__ CMAP,
    const float* __restrict__ dw, const float* __restrict__ db, float* __restrict__ XO){
  int b = blockIdx.x >> 3, cg = blockIdx.x & 7;
  int c0 = cg*32;
  __shared__ __align__(16) float pl[32*360];
  int tid = threadIdx.x;
  for (int t = tid; t < 32*360; t += 256) pl[t] = 0.f;
  __syncthreads();
  const float* yq = Y + (size_t)b*YSTR + QOFF;
  for (int t = tid; t < 32*196; t += 256){
    int cl = t & 31, s = t >> 5;
    int c = c0 + cl;
    int G = s*256 + c;                 // head-major flat index for conv_x2's scramble
    int hh = G / 6272;
    int rem = G - hh*6272;
    int n = rem >> 5, d = rem & 31;
    float cx2 = CMAP[b*256 + c] * yq[n*256 + hh*32 + d];   // sigmoid(cmap)*qs
    float qc  = yq[G];                                     // qc collapses to identity gather
    float v = SCL*(cx2 + qc);
    int i = s/14, j = s - i*14;
    pl[cl*360 + (i+2)*20 + j + 2] = v;
  }
  __syncthreads();
  for (int t = tid; t < 32*14; t += 256){
    int cl = t/14, r = t - cl*14;
    int c = c0 + cl;
    float w25[25];
    #pragma unroll
    for (int u = 0; u < 25; ++u) w25[u] = dw[c*25 + u];
    float acc[14];
    float b2 = 2.f*db[c];
    #pragma unroll
    for (int j = 0; j < 14; ++j) acc[j] = b2;
    conv5x5_row(&pl[cl*360], r, w25, acc);
    float* dst = XO + ((size_t)b*196 + r*14)*256 + c;
    #pragma unroll
    for (int j = 0; j < 14; ++j) dst[j*256] += acc[j];
  }
}

// ---------- final projection: out = XO @ proj_w^T + proj_b ----------
__global__ __launch_bounds__(256) void k_proj(const float* __restrict__ XO, const float* __restrict__ WT,
    const float* __restrict__ pbias, float* __restrict__ OUT){
  int bb = blockIdx.x / 7, nt = blockIdx.x % 7;
  int n0 = nt*28;
  int c = threadIdx.x;
  const float* xb = XO + ((size_t)bb*196 + n0)*256;
  float acc[28];
  #pragma unroll
  for (int r = 0; r < 28; ++r) acc[r] = 0.f;
  for (int k = 0; k < 256; k += 4){
    float w0 = WT[(k+0)*256 + c];
    float w1 = WT[(k+1)*256 + c];
    float w2 = WT[(k+2)*256 + c];
    float w3 = WT[(k+3)*256 + c];
    #pragma unroll
    for (int r = 0; r < 28; ++r){
      float4 xv = *(const float4*)(xb + r*256 + k);   // uniform address -> scalar/L1 path
      acc[r] = fmaf(xv.x, w0, fmaf(xv.y, w1, fmaf(xv.z, w2, fmaf(xv.w, w3, acc[r]))));
    }
  }
  float bv = pbias[c];
  float* dst = OUT + ((size_t)bb*196 + n0)*256 + c;
  #pragma unroll
  for (int r = 0; r < 28; ++r) dst[r*256] = acc[r] + bv;
}

extern "C" void kernel_launch(void* const* d_in, const int* in_sizes, int n_in,
                              void* d_out, int out_size, void* d_ws, size_t ws_size,
                              hipStream_t stream){
  (void)in_sizes; (void)n_in; (void)out_size; (void)ws_size;
  const float* x       = (const float*)d_in[0];
  const float* lka_w   = (const float*)d_in[3];
  const float* lka_b   = (const float*)d_in[4];
  const float* conv5_w = (const float*)d_in[5];
  const float* conv5_b = (const float*)d_in[6];
  const float* caa1_w  = (const float*)d_in[7];
  const float* caa1_b  = (const float*)d_in[8];
  const float* caa2_w  = (const float*)d_in[9];
  const float* caa2_b  = (const float*)d_in[10];
  const float* cam1_w  = (const float*)d_in[11];
  const float* cam1_b  = (const float*)d_in[12];
  const float* cam2_w  = (const float*)d_in[13];
  const float* cam2_b  = (const float*)d_in[14];
  const float* sa_w    = (const float*)d_in[15];
  const float* sa_b    = (const float*)d_in[16];
  const float* ci1_w   = (const float*)d_in[17];
  const float* ci1_b   = (const float*)d_in[18];
  const float* bn_g    = (const float*)d_in[19];
  const float* bn_b    = (const float*)d_in[20];
  const float* ci2_w   = (const float*)d_in[21];
  const float* ci2_b   = (const float*)d_in[22];
  const float* rpbt    = (const float*)d_in[23];
  const float* an_bias = (const float*)d_in[24];
  const float* na_bias = (const float*)d_in[25];
  const float* ah_bias = (const float*)d_in[26];
  const float* aw_bias = (const float*)d_in[27];
  const float* ha_bias = (const float*)d_in[28];
  const float* wa_bias = (const float*)d_in[29];
  const float* dwc_w   = (const float*)d_in[30];
  const float* dwc_b   = (const float*)d_in[31];
  const float* proj_w  = (const float*)d_in[32];
  const float* proj_b  = (const float*)d_in[33];
  float* out = (float*)d_out;
  float* ws = (float*)d_ws;

  float* Y    = ws + WS_Y;
  float* V5   = ws + WS_V5;
  float* AT   = ws + WS_AT;
  float* ATK  = ws + WS_ATK;
  float* CHG  = ws + WS_CHG;
  float* CMAP = ws + WS_CMAP;
  float* PBT  = ws + WS_PBT;
  float* AB   = ws + WS_AB;
  float* X1S  = ws + WS_X1S;
  float* AGV  = ws + WS_AGV;
  float* XO   = ws + WS_XO;
  float* WT   = ws + WS_WT;
  ushort_t* Wh = (ushort_t*)(ws + WS_CWT);

  k_pb   <<<301, 256, 0, stream>>>(an_bias, ah_bias, aw_bias, PBT);
  k_ab   <<<301, 256, 0, stream>>>(na_bias, ha_bias, wa_bias, AB);
  k_wt   <<<256, 256, 0, stream>>>(proj_w, WT);
  k_cw2  <<<6400, 256, 0, stream>>>(conv5_w, Wh);
  k_lka  <<<1024, 256, 0, stream>>>(x, lka_w, lka_b, Y);
  k_conv5<<<512, 256, 0, stream>>>(Y, Wh, conv5_b, V5);
  k_pool <<<128, 256, 0, stream>>>(Y, AT, ATK);
  k_cbam_a<<<128, 256, 0, stream>>>(V5, caa1_w, caa1_b, caa2_w, caa2_b,
                                    cam1_w, cam1_b, cam2_w, cam2_b, CHG);
  k_cbam_b<<<128, 256, 0, stream>>>(V5, CHG, sa_w, sa_b);
  k_attn <<<1024, 256, 0, stream>>>(Y, rpbt, X1S);
  k_cinter<<<128, 256, 0, stream>>>(X1S, ci1_w, ci1_b, bn_g, bn_b, ci2_w, ci2_b, CMAP);
  k_agentv<<<1024, 256, 0, stream>>>(Y, V5, AT, ATK, PBT, AGV);
  k_xo1  <<<1024, 128, 0, stream>>>(Y, AT, ATK, AB, AGV, XO);
  k_dwc  <<<1024, 256, 0, stream>>>(Y, CMAP, dwc_w, dwc_b, XO);
  k_proj <<<896, 256, 0, stream>>>(XO, WT, proj_b, out);
}

// Round 4
// 1056.651 us; speedup vs baseline: 2.0724x; 1.1581x over previous
//
#include <hip/hip_runtime.h>

// Problem constants
#define NB    128
#define NC    256
#define NPOS  196
#define NHEAD 8
#define NAG   49
#define YSTR  150528      // 768*196 per-batch y floats
#define VOFF  50176       // v_raw offset inside y (256*196)
#define QOFF  100352      // q_raw offset inside y (512*196)
#define SCL   0.17677669529663687f   // 32^-0.5

// Workspace layout (floats). Total = 38,885,440 floats = 155.5 MB.
#define WS_Y    0u
#define WS_V5   19267584u
#define WS_AT   25690112u
#define WS_ATK  27295744u
#define WS_CHG  28901376u
#define WS_CMAP 28934144u
#define WS_PBT  28966912u
#define WS_AB   29043744u
#define WS_X1S  29120576u
#define WS_AGV  29153344u
#define WS_XO   30758976u
#define WS_WT   37181504u
#define WS_CWT  37247040u   // Wh: 1.6M ushort (fp16 conv5 weights, [tap][co][ci])

typedef __attribute__((ext_vector_type(8))) _Float16 half8;
typedef __attribute__((ext_vector_type(8))) short short8;
typedef __attribute__((ext_vector_type(4))) float f32x4;
typedef unsigned short ushort_t;
typedef unsigned int uint_t;

__device__ __forceinline__ float sigmoidf_(float x){ return 1.0f/(1.0f+__expf(-x)); }

// bilinear upsample 7x7 -> 14x14 sample at (i,j), matching reference grid()
__device__ __forceinline__ float bilin7(const float* __restrict__ src, int i, int j){
  float pi = fmaxf(0.5f*(float)i - 0.25f, 0.f);
  int i0 = (int)pi; if (i0 > 6) i0 = 6;
  int i1 = i0 + 1;  if (i1 > 6) i1 = 6;
  float li = pi - (float)i0;
  float pj = fmaxf(0.5f*(float)j - 0.25f, 0.f);
  int j0 = (int)pj; if (j0 > 6) j0 = 6;
  int j1 = j0 + 1;  if (j1 > 6) j1 = 6;
  float lj = pj - (float)j0;
  float v00 = src[i0*7+j0], v01 = src[i0*7+j1];
  float v10 = src[i1*7+j0], v11 = src[i1*7+j1];
  float t0 = v00*(1.f-lj) + v01*lj;
  float t1 = v10*(1.f-lj) + v11*lj;
  return t0*(1.f-li) + t1*li;
}

// 5x5 conv over a zero-padded [18][20] plane, producing one 14-wide output row r.
__device__ __forceinline__ void conv5x5_row(const float* __restrict__ plane, int r,
                                            const float* __restrict__ w25, float* acc14){
  #pragma unroll
  for (int di = 0; di < 5; ++di){
    const float4* pr = (const float4*)(plane + (r+di)*20);
    float4 p0 = pr[0], p1 = pr[1], p2 = pr[2], p3 = pr[3], p4 = pr[4];
    float row[20] = {p0.x,p0.y,p0.z,p0.w, p1.x,p1.y,p1.z,p1.w, p2.x,p2.y,p2.z,p2.w,
                     p3.x,p3.y,p3.z,p3.w, p4.x,p4.y,p4.z,p4.w};
    #pragma unroll
    for (int dj = 0; dj < 5; ++dj){
      float w = w25[di*5+dj];
      #pragma unroll
      for (int j = 0; j < 14; ++j) acc14[j] = fmaf(row[j+dj], w, acc14[j]);
    }
  }
}

// ---------- prep kernels ----------
__global__ void k_pb(const float* __restrict__ an, const float* __restrict__ ah,
                     const float* __restrict__ aw, float* __restrict__ PBT){
  int t = blockIdx.x*256 + threadIdx.x;
  if (t >= NHEAD*NPOS*NAG) return;
  int a = t % NAG;
  int r = t / NAG;
  int n = r % NPOS;
  int h = r / NPOS;
  int i = n/14, j = n - (n/14)*14;
  float v = bilin7(an + ((size_t)h*NAG + a)*49, i, j);
  v += ah[((size_t)h*NAG + a)*14 + i] + aw[((size_t)h*NAG + a)*14 + j];
  PBT[t] = v;   // [h][n][a]
}

__global__ void k_ab(const float* __restrict__ na, const float* __restrict__ ha,
                     const float* __restrict__ wa, float* __restrict__ AB){
  int t = blockIdx.x*256 + threadIdx.x;
  if (t >= NHEAD*NPOS*NAG) return;
  int a = t % NAG;
  int r = t / NAG;
  int n = r % NPOS;
  int h = r / NPOS;
  int i = n/14, j = n - (n/14)*14;
  float v = bilin7(na + ((size_t)h*NAG + a)*49, i, j);
  v += ha[((size_t)h*14 + i)*NAG + a] + wa[((size_t)h*14 + j)*NAG + a];
  AB[t] = v;    // [h][n][a]
}

__global__ void k_wt(const float* __restrict__ pw, float* __restrict__ WT){
  int t = blockIdx.x*256 + threadIdx.x;
  if (t >= 65536) return;
  int k = t >> 8, c = t & 255;
  WT[t] = pw[c*256 + k];          // WT[k][c] = proj_w[c][k]
}

// conv5 weights -> fp16, layout [tap][co][ci]
__global__ void k_cw2(const float* __restrict__ cw, ushort_t* __restrict__ Wh){
  int t = blockIdx.x*256 + threadIdx.x;
  if (t >= 1638400) return;
  int ci = t & 255;
  int r  = t >> 8;
  int co = r & 255;
  int tap = r >> 8;
  _Float16 h = (_Float16)cw[((size_t)co*256 + ci)*25 + tap];
  Wh[t] = __builtin_bit_cast(ushort_t, h);
}

// ---------- lka depthwise-ish conv (groups=256, 3 outputs per input channel) ----------
__global__ __launch_bounds__(256) void k_lka(const float* __restrict__ x, const float* __restrict__ lw,
                                             const float* __restrict__ lb, float* __restrict__ Y){
  int b = blockIdx.x >> 3, gb = blockIdx.x & 7;
  int g0 = gb*32;                               // input channels [g0,g0+32)
  __shared__ __align__(16) float pl[32*360];    // [ch][18*20] padded planes
  int tid = threadIdx.x;
  for (int t = tid; t < 32*360; t += 256) pl[t] = 0.f;
  __syncthreads();
  for (int t = tid; t < 32*196; t += 256){
    int gl = t & 31, s = t >> 5;
    int i = s/14, j = s - i*14;
    pl[gl*360 + (i+2)*20 + j + 2] = x[((size_t)b*196 + s)*256 + g0 + gl];
  }
  __syncthreads();
  for (int t = tid; t < 96*14; t += 256){
    int ocl = t/14, r = t - ocl*14;
    int o  = g0*3 + ocl;          // output channel; uses input channel o/3
    int gl = ocl/3;
    float w25[25];
    #pragma unroll
    for (int u = 0; u < 25; ++u) w25[u] = lw[o*25 + u];
    float acc[14];
    float bv = lb[o];
    #pragma unroll
    for (int j = 0; j < 14; ++j) acc[j] = bv;
    conv5x5_row(&pl[gl*360], r, w25, acc);
    float* dst = Y + ((size_t)b*768 + o)*196 + r*14;
    #pragma unroll
    for (int j = 0; j < 14; ++j) dst[j] = acc[j];
  }
}

// ---------- conv5 via fp16 MFMA implicit GEMM ----------
__global__ __launch_bounds__(256, 2) void k_conv5(const float* __restrict__ Y,
    const ushort_t* __restrict__ Wh, const float* __restrict__ cb, float* __restrict__ V5){
  int b = blockIdx.x >> 2, cog = blockIdx.x & 3;
  int co0 = cog*64;
  __shared__ __align__(16) ushort_t Pt[360*40];     // fp16 A: [pos][ci32 swizzled]
  __shared__ __align__(16) ushort_t Wsm[5*64*40];   // fp16 B: [tap-of-row][co][ci32 swizzled]
  __shared__ float T[32*200];                       // epilogue transpose
  int tid  = threadIdx.x;
  int lane = tid & 63, wv = tid >> 6;
  int mrow = lane & 15, quad = lane >> 4;

  // zero-fill Pt once; borders stay zero across chunks
  for (int t = tid; t < 7200; t += 256) ((uint_t*)Pt)[t] = 0;

  // per-lane A plane-row base per m-tile (unpadded base; taps add di*20+dj)
  int prow[4];
  #pragma unroll
  for (int mt = 0; mt < 4; ++mt){
    int s = wv*64 + mt*16 + mrow;
    int p0 = 0;
    if (s < 196){ int i = s/14, j = s - i*14; p0 = i*20 + j; }
    prow[mt] = p0;
  }

  f32x4 acc[4][4];
  #pragma unroll
  for (int mt = 0; mt < 4; ++mt)
    #pragma unroll
    for (int nt = 0; nt < 4; ++nt) acc[mt][nt] = (f32x4){0.f,0.f,0.f,0.f};

  const float* src = Y + (size_t)b*YSTR + VOFF;   // v_raw [ci][s]
  int wco = tid >> 2, wpart = tid & 3;            // W-staging roles

  #pragma unroll 1
  for (int cc = 0; cc < 8; ++cc){
    __syncthreads();
    // stage A: 32 ci planes -> fp16 swizzled [pos][ci]
    if (tid < 196){
      int s = tid; int i = s/14, j = s - i*14;
      int p = (i+2)*20 + (j+2);
      const float* s0 = src + (cc*32)*196 + s;
      #pragma unroll
      for (int cp = 0; cp < 16; ++cp){
        float v0 = s0[(2*cp)*196];
        float v1 = s0[(2*cp+1)*196];
        _Float16 h0 = (_Float16)v0, h1 = (_Float16)v1;
        uint_t pk = (uint_t)__builtin_bit_cast(ushort_t, h0)
                  | ((uint_t)__builtin_bit_cast(ushort_t, h1) << 16);
        int q = cp >> 2;
        *(uint_t*)&Pt[p*40 + (((q ^ p) & 3) << 3) + ((2*cp) & 7)] = pk;
      }
    }
    #pragma unroll 1
    for (int di = 0; di < 5; ++di){
      __syncthreads();      // Wsm free to overwrite; also fences A writes (di=0)
      // stage W: taps di*5..di*5+4, 64 co x 32 ci fp16 each
      #pragma unroll
      for (int tp = 0; tp < 5; ++tp){
        int tap = di*5 + tp;
        const short8 g = *(const short8*)(Wh + ((size_t)tap*256 + co0 + wco)*256 + cc*32 + wpart*8);
        *(short8*)&Wsm[(tp*64 + wco)*40 + (((wpart ^ wco) & 3) << 3)] = g;
      }
      __syncthreads();
      #pragma unroll
      for (int dj = 0; dj < 5; ++dj){
        half8 a[4], bb[4];
        #pragma unroll
        for (int nt = 0; nt < 4; ++nt){
          int co = nt*16 + mrow;
          bb[nt] = *(const half8*)&Wsm[(dj*64 + co)*40 + (((quad ^ co) & 3) << 3)];
        }
        #pragma unroll
        for (int mt = 0; mt < 4; ++mt){
          int p = prow[mt] + di*20 + dj;
          a[mt] = *(const half8*)&Pt[p*40 + (((quad ^ p) & 3) << 3)];
        }
        #pragma unroll
        for (int mt = 0; mt < 4; ++mt)
          #pragma unroll
          for (int nt = 0; nt < 4; ++nt)
            acc[mt][nt] = __builtin_amdgcn_mfma_f32_16x16x32_f16(a[mt], bb[nt], acc[mt][nt], 0, 0, 0);
      }
    }
  }

  // epilogue: transpose through LDS, then stores into scrambled v5
  #pragma unroll
  for (int hf = 0; hf < 2; ++hf){
    __syncthreads();
    #pragma unroll
    for (int ntl = 0; ntl < 2; ++ntl){
      int nt = hf*2 + ntl;
      int col = ntl*16 + mrow;            // co local within half (0..31)
      #pragma unroll
      for (int mt = 0; mt < 4; ++mt){
        int sbase = wv*64 + mt*16 + quad*4;
        #pragma unroll
        for (int r = 0; r < 4; ++r){
          int s = sbase + r;
          if (s < 196) T[col*200 + s] = acc[mt][nt][r];
        }
      }
    }
    __syncthreads();
    for (int t = tid; t < 6272; t += 256){
      int cl = t / 196;                   // co local 0..31
      int f = (co0 + hf*32)*196 + t;
      float val = T[t + cl*4] + cb[co0 + hf*32 + cl];
      V5[(size_t)b*50176 + (size_t)(f & 255)*196 + (f >> 8)] = val;
    }
  }
}

// ---------- agent token pooling: at = 2x2-mean of q_raw, atk = 2x2-max of k_raw ----------
__global__ __launch_bounds__(256) void k_pool(const float* __restrict__ Y, float* __restrict__ AT, float* __restrict__ ATK){
  int b = blockIdx.x; int c = threadIdx.x;
  const float* qp = Y + ((size_t)b*768 + 512 + c)*196;
  const float* kp = Y + ((size_t)b*768 + c)*196;
  for (int a = 0; a < 49; ++a){
    int p1 = a/7, p2 = a - p1*7;
    int s = p1*28 + p2*2;
    float q0 = qp[s], q1 = qp[s+1], q2 = qp[s+14], q3 = qp[s+15];
    AT[((size_t)b*49 + a)*256 + c] = 0.25f*(q0+q1+q2+q3);
    float k0 = kp[s], k1 = kp[s+1], k2 = kp[s+14], k3 = kp[s+15];
    ATK[((size_t)b*49 + a)*256 + c] = fmaxf(fmaxf(k0,k1), fmaxf(k2,k3));
  }
}

// ---------- cbam stage A: channel gate ----------
__global__ __launch_bounds__(256) void k_cbam_a(const float* __restrict__ V5,
    const float* __restrict__ caa1w, const float* __restrict__ caa1b,
    const float* __restrict__ caa2w, const float* __restrict__ caa2b,
    const float* __restrict__ cam1w, const float* __restrict__ cam1b,
    const float* __restrict__ cam2w, const float* __restrict__ cam2b,
    float* __restrict__ CHG){
  int b = blockIdx.x, c = threadIdx.x;
  __shared__ float avg[256], mx[256], t1[16], t2[16];
  const float* pp = V5 + ((size_t)b*256 + c)*196;
  float s = 0.f, m = -1e30f;
  for (int i = 0; i < 196; ++i){ float v = pp[i]; s += v; m = fmaxf(m, v); }
  avg[c] = s * (1.0f/196.0f); mx[c] = m;
  __syncthreads();
  if (c < 16){
    float a1 = caa1b[c], a2 = cam1b[c];
    #pragma unroll 4
    for (int k = 0; k < 256; ++k){
      a1 = fmaf(caa1w[(c*256 + k)*9 + 4], avg[k], a1);   // 3x3 center tap
      a2 = fmaf(cam1w[c*256 + k], mx[k], a2);            // 1x1
    }
    t1[c] = fmaxf(a1, 0.f);
    t2[c] = fmaxf(a2, 0.f);
  }
  __syncthreads();
  float y1 = caa2b[c], y2 = cam2b[c];
  #pragma unroll
  for (int k = 0; k < 16; ++k){
    y1 = fmaf(caa2w[(c*16 + k)*9 + 4], t1[k], y1);
    y2 = fmaf(cam2w[c*16 + k], t2[k], y2);
  }
  CHG[b*256 + c] = sigmoidf_(sigmoidf_(y1) + sigmoidf_(y2));
}

// ---------- cbam stage B: spatial mask (9x9 pad4 over [mean,max]) + in-place gate ----------
__global__ __launch_bounds__(256) void k_cbam_b(float* __restrict__ V5, const float* __restrict__ CHG,
    const float* __restrict__ saw, const float* __restrict__ sab){
  int b = blockIdx.x; int tid = threadIdx.x;
  __shared__ float chg[256];
  __shared__ float mp[22*22], xp[22*22];
  __shared__ float mk[196];
  chg[tid] = CHG[b*256 + tid];
  for (int t = tid; t < 484; t += 256){ mp[t] = 0.f; xp[t] = 0.f; }
  __syncthreads();
  if (tid < 196){
    int i = tid/14, j = tid - i*14;
    float s = 0.f, m = -1e30f;
    const float* vb = V5 + (size_t)b*256*196 + tid;
    for (int c = 0; c < 256; ++c){
      float v = chg[c] * vb[c*196];
      s += v; m = fmaxf(m, v);
    }
    mp[(i+4)*22 + j+4] = s*(1.f/256.f);
    xp[(i+4)*22 + j+4] = m;
  }
  __syncthreads();
  if (tid < 196){
    int i = tid/14, j = tid - i*14;
    float acc = sab[0];
    for (int di = 0; di < 9; ++di){
      #pragma unroll
      for (int dj = 0; dj < 9; ++dj){
        acc = fmaf(mp[(i+di)*22 + j+dj], saw[di*9+dj], acc);
        acc = fmaf(xp[(i+di)*22 + j+dj], saw[81 + di*9+dj], acc);
      }
    }
    mk[tid] = sigmoidf_(acc);
  }
  __syncthreads();
  if (tid < 196){
    float m = mk[tid];
    float* vb = V5 + (size_t)b*256*196 + tid;
    for (int c = 0; c < 256; ++c) vb[c*196] = chg[c]*vb[c*196]*m;
  }
}

// ---------- big NxN attention; only the per-(b,c) mean of x1 is needed downstream ----------
__global__ __launch_bounds__(256) void k_attn(const float* __restrict__ Y, const float* __restrict__ rpbt,
                                              float* __restrict__ X1S){
  int b = blockIdx.x >> 3, h = blockIdx.x & 7;
  __shared__ float rp[729];
  __shared__ float xs[196*33];
  int tid = threadIdx.x;
  for (int t = tid; t < 729; t += 256) rp[t] = rpbt[t*8 + h];
  __syncthreads();
  const float* yb = Y + (size_t)b*YSTR;
  if (tid < 196){
    int n = tid;
    float q[32];
    {
      const float4* q4 = (const float4*)(yb + QOFF + (size_t)n*256 + h*32);
      #pragma unroll
      for (int u = 0; u < 8; ++u){
        float4 v = q4[u];
        q[4*u] = v.x*SCL; q[4*u+1] = v.y*SCL; q[4*u+2] = v.z*SCL; q[4*u+3] = v.w*SCL;
      }
    }
    int ri = n/14, ci = n - ri*14;
    int bidx = (ri + 13)*27 + (ci + 13);
    float acc[32];
    #pragma unroll
    for (int d = 0; d < 32; ++d) acc[d] = 0.f;
    float l = 0.f;
    int rj = 0, cj = 0;
    for (int j = 0; j < 196; ++j){
      const float4* k4 = (const float4*)(yb + (size_t)j*256 + h*32);
      float s0 = 0.f, s1 = 0.f;
      #pragma unroll
      for (int u = 0; u < 8; u += 2){
        float4 a = k4[u], bb = k4[u+1];
        s0 = fmaf(q[4*u+0],a.x, fmaf(q[4*u+1],a.y, fmaf(q[4*u+2],a.z, fmaf(q[4*u+3],a.w, s0))));
        s1 = fmaf(q[4*u+4],bb.x, fmaf(q[4*u+5],bb.y, fmaf(q[4*u+6],bb.z, fmaf(q[4*u+7],bb.w, s1))));
      }
      float s = s0 + s1 + rp[bidx - rj*27 - cj];
      float p = __expf(s);       // logits are O(0.1): max-free softmax is safe
      l += p;
      const float4* v4 = (const float4*)(yb + VOFF + (size_t)j*256 + h*32);
      #pragma unroll
      for (int u = 0; u < 8; ++u){
        float4 vv = v4[u];
        acc[4*u]   = fmaf(p, vv.x, acc[4*u]);
        acc[4*u+1] = fmaf(p, vv.y, acc[4*u+1]);
        acc[4*u+2] = fmaf(p, vv.z, acc[4*u+2]);
        acc[4*u+3] = fmaf(p, vv.w, acc[4*u+3]);
      }
      if (++cj == 14){ cj = 0; ++rj; }
    }
    float inv = 1.f/l;
    #pragma unroll
    for (int d = 0; d < 32; ++d) xs[n*33 + d] = acc[d]*inv;
  }
  __syncthreads();
  if (tid < 32){
    float s = 0.f;
    for (int n = 0; n < 196; ++n) s += xs[n*33 + tid];
    X1S[(size_t)b*256 + h*32 + tid] = s*(1.f/196.f);   // mean over n of x1[b,:,c]
  }
}

// ---------- chan_inter on x1 mean -> sigmoid gate CMAP ----------
__global__ __launch_bounds__(256) void k_cinter(const float* __restrict__ X1S,
    const float* __restrict__ ci1w, const float* __restrict__ ci1b,
    const float* __restrict__ bng, const float* __restrict__ bnb,
    const float* __restrict__ ci2w, const float* __restrict__ ci2b, float* __restrict__ CMAP){
  int b = blockIdx.x, c = threadIdx.x;
  __shared__ float p[256], tt[16];
  p[c] = X1S[b*256 + c];
  __syncthreads();
  if (c < 16){
    float a = ci1b[c];
    #pragma unroll 4
    for (int k = 0; k < 256; ++k) a = fmaf(ci1w[(c*256+k)*25 + 12], p[k], a);  // 5x5 center
    const float invs = 0.9999950000375f;   // 1/sqrt(1+1e-5)
    tt[c] = fmaxf(fmaf(bng[c]*invs, a, bnb[c]), 0.f);
  }
  __syncthreads();
  float a = ci2b[c];
  #pragma unroll
  for (int k = 0; k < 16; ++k) a = fmaf(ci2w[(c*16+k)*25 + 12], tt[k], a);
  CMAP[b*256 + c] = sigmoidf_(a);
}

// ---------- agent_v = softmax(at*scale@K^T+pb)@V1 + softmax(atk*scale@Q^T+pb)@V ----------
__global__ __launch_bounds__(256) void k_agentv(const float* __restrict__ Y, const float* __restrict__ V5,
    const float* __restrict__ AT, const float* __restrict__ ATK,
    const float* __restrict__ PBT, float* __restrict__ AGV){
  int b = blockIdx.x >> 3, h = blockIdx.x & 7;
  __shared__ float S[196*53];
  __shared__ float part[4*64];
  int tid = threadIdx.x;
  int wv = tid >> 6, lane = tid & 63;
  const float* yb  = Y + (size_t)b*YSTR;
  const float* vcb = V5 + (size_t)b*256*196;
  float ar[32], akr[32];
  if (lane < 49){
    const float4* ap = (const float4*)(AT  + ((size_t)b*49 + lane)*256 + h*32);
    const float4* kp = (const float4*)(ATK + ((size_t)b*49 + lane)*256 + h*32);
    #pragma unroll
    for (int u = 0; u < 8; ++u){
      float4 a = ap[u], k = kp[u];
      ar[4*u]=a.x; ar[4*u+1]=a.y; ar[4*u+2]=a.z; ar[4*u+3]=a.w;
      akr[4*u]=k.x; akr[4*u+1]=k.y; akr[4*u+2]=k.z; akr[4*u+3]=k.w;
    }
  }
  float acc[8];
  #pragma unroll
  for (int d = 0; d < 8; ++d) acc[d] = 0.f;
  int d0 = wv*8;

  // ---- pass 0: agent_attn (ar . K)*scale + pb ; x V1 (vc) ----
  {
    float lsum = 0.f;
    if (lane < 49){
      for (int n = wv; n < 196; n += 4){
        const float4* r4 = (const float4*)(yb + (size_t)n*256 + h*32);
        float s = 0.f;
        #pragma unroll
        for (int u = 0; u < 8; ++u){
          float4 v = r4[u];
          s = fmaf(ar[4*u],v.x, fmaf(ar[4*u+1],v.y, fmaf(ar[4*u+2],v.z, fmaf(ar[4*u+3],v.w, s))));
        }
        s = fmaf(s, SCL, PBT[((size_t)h*196 + n)*49 + lane]);
        float e = __expf(s);
        S[n*53 + lane] = e;
        lsum += e;
      }
    }
    part[wv*64 + lane] = lsum;
    __syncthreads();
    if (lane < 49){
      float l = part[lane] + part[64+lane] + part[128+lane] + part[192+lane];
      float inv = 1.f/l;
      float a8[8];
      #pragma unroll
      for (int d = 0; d < 8; ++d) a8[d] = 0.f;
      const float* vp = vcb + (h*32 + d0)*196;
      for (int n = 0; n < 196; ++n){
        float pv = S[n*53 + lane];
        #pragma unroll
        for (int d = 0; d < 8; ++d) a8[d] = fmaf(pv, vp[d*196 + n], a8[d]);
      }
      #pragma unroll
      for (int d = 0; d < 8; ++d) acc[d] += inv*a8[d];
    }
    __syncthreads();
  }
  // ---- pass 1: agent_attn1 (akr . Q_raw)*scale^2 + pb ; x V (y) ----
  {
    float lsum = 0.f;
    if (lane < 49){
      for (int n = wv; n < 196; n += 4){
        const float4* r4 = (const float4*)(yb + QOFF + (size_t)n*256 + h*32);
        float s = 0.f;
        #pragma unroll
        for (int u = 0; u < 8; ++u){
          float4 v = r4[u];
          s = fmaf(akr[4*u],v.x, fmaf(akr[4*u+1],v.y, fmaf(akr[4*u+2],v.z, fmaf(akr[4*u+3],v.w, s))));
        }
        s = fmaf(s, 0.03125f, PBT[((size_t)h*196 + n)*49 + lane]);
        float e = __expf(s);
        S[n*53 + lane] = e;
        lsum += e;
      }
    }
    part[wv*64 + lane] = lsum;
    __syncthreads();
    if (lane < 49){
      float l = part[lane] + part[64+lane] + part[128+lane] + part[192+lane];
      float inv = 1.f/l;
      float a8[8];
      #pragma unroll
      for (int d = 0; d < 8; ++d) a8[d] = 0.f;
      for (int n = 0; n < 196; ++n){
        float pv = S[n*53 + lane];
        const float* vp = yb + VOFF + (size_t)n*256 + h*32 + d0;
        #pragma unroll
        for (int d = 0; d < 8; ++d) a8[d] = fmaf(pv, vp[d], a8[d]);
      }
      #pragma unroll
      for (int d = 0; d < 8; ++d) acc[d] += inv*a8[d];
    }
  }
  if (lane < 49){
    float* dst = AGV + (((size_t)(b*8 + h)*49) + lane)*32 + d0;
    #pragma unroll
    for (int d = 0; d < 8; ++d) dst[d] = acc[d];
  }
}

// ---------- xo1 = (softmax(q*scale@at^T+ab) + softmax(k*scale@atk^T+ab)) @ agent_v ----------
// One-pass combined logits (q and k share the AB bias load), single P buffer,
// 4 waves, epilogue split by (row, d-half). Latency-bound fix: 2x waves,
// half the barriers, half the LDS of the previous version.
__global__ __launch_bounds__(256) void k_xo1(const float* __restrict__ Y,
    const float* __restrict__ AT, const float* __restrict__ ATK,
    const float* __restrict__ AB, const float* __restrict__ AGV, float* __restrict__ XO){
  int b = blockIdx.x >> 3, h = blockIdx.x & 7;
  __shared__ float P[98*53];
  __shared__ float sAGV[49*32];
  int tid = threadIdx.x;
  int wv = tid >> 6, lane = tid & 63;
  const float* yb = Y + (size_t)b*YSTR;
  float ar[32], akr[32];
  if (lane < 49){
    const float4* ap = (const float4*)(AT  + ((size_t)b*49 + lane)*256 + h*32);
    const float4* kp = (const float4*)(ATK + ((size_t)b*49 + lane)*256 + h*32);
    #pragma unroll
    for (int u = 0; u < 8; ++u){
      float4 a = ap[u], k = kp[u];
      ar[4*u]=a.x; ar[4*u+1]=a.y; ar[4*u+2]=a.z; ar[4*u+3]=a.w;
      akr[4*u]=k.x; akr[4*u+1]=k.y; akr[4*u+2]=k.z; akr[4*u+3]=k.w;
    }
  }
  {
    const float* agvb = AGV + (size_t)(b*8 + h)*49*32;
    for (int t = tid; t < 1568; t += 256) sAGV[t] = agvb[t];
  }
  #pragma unroll 1
  for (int chunk = 0; chunk < 2; ++chunk){
    __syncthreads();    // P safe to overwrite; (chunk 0: also fences sAGV stores)
    for (int i = wv; i < 98; i += 4){
      int n = chunk*98 + i;
      float eq = 0.f, ek = 0.f;
      if (lane < 49){
        float ab = AB[((size_t)h*196 + n)*49 + lane];
        const float4* q4 = (const float4*)(yb + QOFF + (size_t)n*256 + h*32);
        const float4* k4 = (const float4*)(yb + (size_t)n*256 + h*32);
        float sq = 0.f, sk = 0.f;
        #pragma unroll
        for (int u = 0; u < 8; ++u){
          float4 qv = q4[u], kv = k4[u];
          sq = fmaf(ar[4*u],qv.x, fmaf(ar[4*u+1],qv.y, fmaf(ar[4*u+2],qv.z, fmaf(ar[4*u+3],qv.w, sq))));
          sk = fmaf(akr[4*u],kv.x, fmaf(akr[4*u+1],kv.y, fmaf(akr[4*u+2],kv.z, fmaf(akr[4*u+3],kv.w, sk))));
        }
        eq = __expf(fmaf(sq, 0.03125f, ab));   // (q*scale . at*scale)
        ek = __expf(fmaf(sk, SCL, ab));        // (k*scale . atk)
      }
      float tq = eq, tk = ek;
      #pragma unroll
      for (int o = 32; o > 0; o >>= 1){ tq += __shfl_xor(tq, o); tk += __shfl_xor(tk, o); }
      if (lane < 49) P[i*53 + lane] = eq/tq + ek/tk;
    }
    __syncthreads();
    if (tid < 196){
      int i = tid >> 1, dh = tid & 1;      // row i, d half
      int n = chunk*98 + i;
      float out[16];
      #pragma unroll
      for (int d = 0; d < 16; ++d) out[d] = 0.f;
      const float* pr = &P[i*53];
      #pragma unroll 7
      for (int a = 0; a < 49; ++a){
        float pv = pr[a];
        const float4* g4 = (const float4*)&sAGV[a*32 + dh*16];
        #pragma unroll
        for (int u = 0; u < 4; ++u){
          float4 gv = g4[u];
          out[4*u]   = fmaf(pv, gv.x, out[4*u]);
          out[4*u+1] = fmaf(pv, gv.y, out[4*u+1]);
          out[4*u+2] = fmaf(pv, gv.z, out[4*u+2]);
          out[4*u+3] = fmaf(pv, gv.w, out[4*u+3]);
        }
      }
      float* dst = XO + ((size_t)b*196 + n)*256 + h*32 + dh*16;
      #pragma unroll
      for (int d = 0; d < 16; ++d) dst[d] = out[d];
    }
  }
}

// ---------- fused depthwise conv: dwc(conv_x2 + qc), bias 2*dwc_b, accumulated into XO ----------
__global__ __launch_bounds__(256) void k_dwc(const float* __restrict__ Y, const float* __restrict__ CMAP,
    const float* __restrict__ dw, const float* __restrict__ db, float* __restrict__ XO){
  int b = blockIdx.x >> 3, cg = blockIdx.x & 7;
  int c0 = cg*32;
  __shared__ __align__(16) float pl[32*360];
  int tid = threadIdx.x;
  for (int t = tid; t < 32*360; t += 256) pl[t] = 0.f;
  __syncthreads();
  const float* yq = Y + (size_t)b*YSTR + QOFF;
  for (int t = tid; t < 32*196; t += 256){
    int cl = t & 31, s = t >> 5;
    int c = c0 + cl;
    int G = s*256 + c;                 // head-major flat index for conv_x2's scramble
    int hh = G / 6272;
    int rem = G - hh*6272;
    int n = rem >> 5, d = rem & 31;
    float cx2 = CMAP[b*256 + c] * yq[n*256 + hh*32 + d];   // sigmoid(cmap)*qs
    float qc  = yq[G];                                     // qc collapses to identity gather
    float v = SCL*(cx2 + qc);
    int i = s/14, j = s - i*14;
    pl[cl*360 + (i+2)*20 + j + 2] = v;
  }
  __syncthreads();
  for (int t = tid; t < 32*14; t += 256){
    int cl = t/14, r = t - cl*14;
    int c = c0 + cl;
    float w25[25];
    #pragma unroll
    for (int u = 0; u < 25; ++u) w25[u] = dw[c*25 + u];
    float acc[14];
    float b2 = 2.f*db[c];
    #pragma unroll
    for (int j = 0; j < 14; ++j) acc[j] = b2;
    conv5x5_row(&pl[cl*360], r, w25, acc);
    float* dst = XO + ((size_t)b*196 + r*14)*256 + c;
    #pragma unroll
    for (int j = 0; j < 14; ++j) dst[j*256] += acc[j];
  }
}

// ---------- final projection: out = XO @ proj_w^T + proj_b ----------
__global__ __launch_bounds__(256) void k_proj(const float* __restrict__ XO, const float* __restrict__ WT,
    const float* __restrict__ pbias, float* __restrict__ OUT){
  int bb = blockIdx.x / 7, nt = blockIdx.x % 7;
  int n0 = nt*28;
  int c = threadIdx.x;
  const float* xb = XO + ((size_t)bb*196 + n0)*256;
  float acc[28];
  #pragma unroll
  for (int r = 0; r < 28; ++r) acc[r] = 0.f;
  for (int k = 0; k < 256; k += 4){
    float w0 = WT[(k+0)*256 + c];
    float w1 = WT[(k+1)*256 + c];
    float w2 = WT[(k+2)*256 + c];
    float w3 = WT[(k+3)*256 + c];
    #pragma unroll
    for (int r = 0; r < 28; ++r){
      float4 xv = *(const float4*)(xb + r*256 + k);   // uniform address -> scalar/L1 path
      acc[r] = fmaf(xv.x, w0, fmaf(xv.y, w1, fmaf(xv.z, w2, fmaf(xv.w, w3, acc[r]))));
    }
  }
  float bv = pbias[c];
  float* dst = OUT + ((size_t)bb*196 + n0)*256 + c;
  #pragma unroll
  for (int r = 0; r < 28; ++r) dst[r*256] = acc[r] + bv;
}

extern "C" void kernel_launch(void* const* d_in, const int* in_sizes, int n_in,
                              void* d_out, int out_size, void* d_ws, size_t ws_size,
                              hipStream_t stream){
  (void)in_sizes; (void)n_in; (void)out_size; (void)ws_size;
  const float* x       = (const float*)d_in[0];
  const float* lka_w   = (const float*)d_in[3];
  const float* lka_b   = (const float*)d_in[4];
  const float* conv5_w = (const float*)d_in[5];
  const float* conv5_b = (const float*)d_in[6];
  const float* caa1_w  = (const float*)d_in[7];
  const float* caa1_b  = (const float*)d_in[8];
  const float* caa2_w  = (const float*)d_in[9];
  const float* caa2_b  = (const float*)d_in[10];
  const float* cam1_w  = (const float*)d_in[11];
  const float* cam1_b  = (const float*)d_in[12];
  const float* cam2_w  = (const float*)d_in[13];
  const float* cam2_b  = (const float*)d_in[14];
  const float* sa_w    = (const float*)d_in[15];
  const float* sa_b    = (const float*)d_in[16];
  const float* ci1_w   = (const float*)d_in[17];
  const float* ci1_b   = (const float*)d_in[18];
  const float* bn_g    = (const float*)d_in[19];
  const float* bn_b    = (const float*)d_in[20];
  const float* ci2_w   = (const float*)d_in[21];
  const float* ci2_b   = (const float*)d_in[22];
  const float* rpbt    = (const float*)d_in[23];
  const float* an_bias = (const float*)d_in[24];
  const float* na_bias = (const float*)d_in[25];
  const float* ah_bias = (const float*)d_in[26];
  const float* aw_bias = (const float*)d_in[27];
  const float* ha_bias = (const float*)d_in[28];
  const float* wa_bias = (const float*)d_in[29];
  const float* dwc_w   = (const float*)d_in[30];
  const float* dwc_b   = (const float*)d_in[31];
  const float* proj_w  = (const float*)d_in[32];
  const float* proj_b  = (const float*)d_in[33];
  float* out = (float*)d_out;
  float* ws = (float*)d_ws;

  float* Y    = ws + WS_Y;
  float* V5   = ws + WS_V5;
  float* AT   = ws + WS_AT;
  float* ATK  = ws + WS_ATK;
  float* CHG  = ws + WS_CHG;
  float* CMAP = ws + WS_CMAP;
  float* PBT  = ws + WS_PBT;
  float* AB   = ws + WS_AB;
  float* X1S  = ws + WS_X1S;
  float* AGV  = ws + WS_AGV;
  float* XO   = ws + WS_XO;
  float* WT   = ws + WS_WT;
  ushort_t* Wh = (ushort_t*)(ws + WS_CWT);

  k_pb   <<<301, 256, 0, stream>>>(an_bias, ah_bias, aw_bias, PBT);
  k_ab   <<<301, 256, 0, stream>>>(na_bias, ha_bias, wa_bias, AB);
  k_wt   <<<256, 256, 0, stream>>>(proj_w, WT);
  k_cw2  <<<6400, 256, 0, stream>>>(conv5_w, Wh);
  k_lka  <<<1024, 256, 0, stream>>>(x, lka_w, lka_b, Y);
  k_conv5<<<512, 256, 0, stream>>>(Y, Wh, conv5_b, V5);
  k_pool <<<128, 256, 0, stream>>>(Y, AT, ATK);
  k_cbam_a<<<128, 256, 0, stream>>>(V5, caa1_w, caa1_b, caa2_w, caa2_b,
                                    cam1_w, cam1_b, cam2_w, cam2_b, CHG);
  k_cbam_b<<<128, 256, 0, stream>>>(V5, CHG, sa_w, sa_b);
  k_attn <<<1024, 256, 0, stream>>>(Y, rpbt, X1S);
  k_cinter<<<128, 256, 0, stream>>>(X1S, ci1_w, ci1_b, bn_g, bn_b, ci2_w, ci2_b, CMAP);
  k_agentv<<<1024, 256, 0, stream>>>(Y, V5, AT, ATK, PBT, AGV);
  k_xo1  <<<1024, 256, 0, stream>>>(Y, AT, ATK, AB, AGV, XO);
  k_dwc  <<<1024, 256, 0, stream>>>(Y, CMAP, dwc_w, dwc_b, XO);
  k_proj <<<896, 256, 0, stream>>>(XO, WT, proj_b, out);
}

// Round 5
// 1040.253 us; speedup vs baseline: 2.1050x; 1.0158x over previous
//
#include <hip/hip_runtime.h>

// Problem constants
#define NB    128
#define NC    256
#define NPOS  196
#define NHEAD 8
#define NAG   49
#define YSTR  150528      // 768*196 per-batch y floats
#define VOFF  50176       // v_raw offset inside y (256*196)
#define QOFF  100352      // q_raw offset inside y (512*196)
#define SCL   0.17677669529663687f   // 32^-0.5

// Workspace layout (floats). Total = 38,885,440 floats = 155.5 MB.
#define WS_Y    0u
#define WS_V5   19267584u
#define WS_AT   25690112u
#define WS_ATK  27295744u
#define WS_CHG  28901376u
#define WS_CMAP 28934144u
#define WS_PBT  28966912u
#define WS_AB   29043744u
#define WS_X1S  29120576u
#define WS_AGV  29153344u
#define WS_XO   30758976u
#define WS_WT   37181504u
#define WS_CWT  37247040u   // Wh: 1.6M ushort (fp16 conv5 weights, [tap][co][ci])

typedef __attribute__((ext_vector_type(8))) _Float16 half8;
typedef __attribute__((ext_vector_type(8))) short short8;
typedef __attribute__((ext_vector_type(4))) float f32x4;
typedef unsigned short ushort_t;
typedef unsigned int uint_t;

__device__ __forceinline__ float sigmoidf_(float x){ return 1.0f/(1.0f+__expf(-x)); }

__device__ __forceinline__ ushort_t f2h(float x){
  _Float16 h = (_Float16)x; return __builtin_bit_cast(ushort_t, h);
}
__device__ __forceinline__ float h2f(ushort_t u){
  return (float)__builtin_bit_cast(_Float16, u);
}

// bilinear upsample 7x7 -> 14x14 sample at (i,j), matching reference grid()
__device__ __forceinline__ float bilin7(const float* __restrict__ src, int i, int j){
  float pi = fmaxf(0.5f*(float)i - 0.25f, 0.f);
  int i0 = (int)pi; if (i0 > 6) i0 = 6;
  int i1 = i0 + 1;  if (i1 > 6) i1 = 6;
  float li = pi - (float)i0;
  float pj = fmaxf(0.5f*(float)j - 0.25f, 0.f);
  int j0 = (int)pj; if (j0 > 6) j0 = 6;
  int j1 = j0 + 1;  if (j1 > 6) j1 = 6;
  float lj = pj - (float)j0;
  float v00 = src[i0*7+j0], v01 = src[i0*7+j1];
  float v10 = src[i1*7+j0], v11 = src[i1*7+j1];
  float t0 = v00*(1.f-lj) + v01*lj;
  float t1 = v10*(1.f-lj) + v11*lj;
  return t0*(1.f-li) + t1*li;
}

// 5x5 conv over a zero-padded [18][20] plane, producing one 14-wide output row r.
__device__ __forceinline__ void conv5x5_row(const float* __restrict__ plane, int r,
                                            const float* __restrict__ w25, float* acc14){
  #pragma unroll
  for (int di = 0; di < 5; ++di){
    const float4* pr = (const float4*)(plane + (r+di)*20);
    float4 p0 = pr[0], p1 = pr[1], p2 = pr[2], p3 = pr[3], p4 = pr[4];
    float row[20] = {p0.x,p0.y,p0.z,p0.w, p1.x,p1.y,p1.z,p1.w, p2.x,p2.y,p2.z,p2.w,
                     p3.x,p3.y,p3.z,p3.w, p4.x,p4.y,p4.z,p4.w};
    #pragma unroll
    for (int dj = 0; dj < 5; ++dj){
      float w = w25[di*5+dj];
      #pragma unroll
      for (int j = 0; j < 14; ++j) acc14[j] = fmaf(row[j+dj], w, acc14[j]);
    }
  }
}

// ---------- prep kernels ----------
__global__ void k_pb(const float* __restrict__ an, const float* __restrict__ ah,
                     const float* __restrict__ aw, float* __restrict__ PBT){
  int t = blockIdx.x*256 + threadIdx.x;
  if (t >= NHEAD*NPOS*NAG) return;
  int a = t % NAG;
  int r = t / NAG;
  int n = r % NPOS;
  int h = r / NPOS;
  int i = n/14, j = n - (n/14)*14;
  float v = bilin7(an + ((size_t)h*NAG + a)*49, i, j);
  v += ah[((size_t)h*NAG + a)*14 + i] + aw[((size_t)h*NAG + a)*14 + j];
  PBT[t] = v;   // [h][n][a]
}

__global__ void k_ab(const float* __restrict__ na, const float* __restrict__ ha,
                     const float* __restrict__ wa, float* __restrict__ AB){
  int t = blockIdx.x*256 + threadIdx.x;
  if (t >= NHEAD*NPOS*NAG) return;
  int a = t % NAG;
  int r = t / NAG;
  int n = r % NPOS;
  int h = r / NPOS;
  int i = n/14, j = n - (n/14)*14;
  float v = bilin7(na + ((size_t)h*NAG + a)*49, i, j);
  v += ha[((size_t)h*14 + i)*NAG + a] + wa[((size_t)h*14 + j)*NAG + a];
  AB[t] = v;    // [h][n][a]
}

__global__ void k_wt(const float* __restrict__ pw, float* __restrict__ WT){
  int t = blockIdx.x*256 + threadIdx.x;
  if (t >= 65536) return;
  int k = t >> 8, c = t & 255;
  WT[t] = pw[c*256 + k];          // WT[k][c] = proj_w[c][k]
}

// conv5 weights -> fp16, layout [tap][co][ci]
__global__ void k_cw2(const float* __restrict__ cw, ushort_t* __restrict__ Wh){
  int t = blockIdx.x*256 + threadIdx.x;
  if (t >= 1638400) return;
  int ci = t & 255;
  int r  = t >> 8;
  int co = r & 255;
  int tap = r >> 8;
  Wh[t] = f2h(cw[((size_t)co*256 + ci)*25 + tap]);
}

// ---------- lka depthwise-ish conv (groups=256, 3 outputs per input channel) ----------
__global__ __launch_bounds__(256) void k_lka(const float* __restrict__ x, const float* __restrict__ lw,
                                             const float* __restrict__ lb, float* __restrict__ Y){
  int b = blockIdx.x >> 3, gb = blockIdx.x & 7;
  int g0 = gb*32;                               // input channels [g0,g0+32)
  __shared__ __align__(16) float pl[32*360];    // [ch][18*20] padded planes
  int tid = threadIdx.x;
  for (int t = tid; t < 32*360; t += 256) pl[t] = 0.f;
  __syncthreads();
  for (int t = tid; t < 32*196; t += 256){
    int gl = t & 31, s = t >> 5;
    int i = s/14, j = s - i*14;
    pl[gl*360 + (i+2)*20 + j + 2] = x[((size_t)b*196 + s)*256 + g0 + gl];
  }
  __syncthreads();
  for (int t = tid; t < 96*14; t += 256){
    int ocl = t/14, r = t - ocl*14;
    int o  = g0*3 + ocl;          // output channel; uses input channel o/3
    int gl = ocl/3;
    float w25[25];
    #pragma unroll
    for (int u = 0; u < 25; ++u) w25[u] = lw[o*25 + u];
    float acc[14];
    float bv = lb[o];
    #pragma unroll
    for (int j = 0; j < 14; ++j) acc[j] = bv;
    conv5x5_row(&pl[gl*360], r, w25, acc);
    float* dst = Y + ((size_t)b*768 + o)*196 + r*14;
    #pragma unroll
    for (int j = 0; j < 14; ++j) dst[j] = acc[j];
  }
}

// ---------- conv5 via fp16 MFMA implicit GEMM ----------
__global__ __launch_bounds__(256, 2) void k_conv5(const float* __restrict__ Y,
    const ushort_t* __restrict__ Wh, const float* __restrict__ cb, float* __restrict__ V5){
  int b = blockIdx.x >> 2, cog = blockIdx.x & 3;
  int co0 = cog*64;
  __shared__ __align__(16) ushort_t Pt[360*40];     // fp16 A: [pos][ci32 swizzled]
  __shared__ __align__(16) ushort_t Wsm[5*64*40];   // fp16 B: [tap-of-row][co][ci32 swizzled]
  __shared__ float T[32*200];                       // epilogue transpose
  int tid  = threadIdx.x;
  int lane = tid & 63, wv = tid >> 6;
  int mrow = lane & 15, quad = lane >> 4;

  // zero-fill Pt once; borders stay zero across chunks
  for (int t = tid; t < 7200; t += 256) ((uint_t*)Pt)[t] = 0;

  // per-lane A plane-row base per m-tile (unpadded base; taps add di*20+dj)
  int prow[4];
  #pragma unroll
  for (int mt = 0; mt < 4; ++mt){
    int s = wv*64 + mt*16 + mrow;
    int p0 = 0;
    if (s < 196){ int i = s/14, j = s - i*14; p0 = i*20 + j; }
    prow[mt] = p0;
  }

  f32x4 acc[4][4];
  #pragma unroll
  for (int mt = 0; mt < 4; ++mt)
    #pragma unroll
    for (int nt = 0; nt < 4; ++nt) acc[mt][nt] = (f32x4){0.f,0.f,0.f,0.f};

  const float* src = Y + (size_t)b*YSTR + VOFF;   // v_raw [ci][s]
  int wco = tid >> 2, wpart = tid & 3;            // W-staging roles

  #pragma unroll 1
  for (int cc = 0; cc < 8; ++cc){
    __syncthreads();
    // stage A: 32 ci planes -> fp16 swizzled [pos][ci]
    if (tid < 196){
      int s = tid; int i = s/14, j = s - i*14;
      int p = (i+2)*20 + (j+2);
      const float* s0 = src + (cc*32)*196 + s;
      #pragma unroll
      for (int cp = 0; cp < 16; ++cp){
        float v0 = s0[(2*cp)*196];
        float v1 = s0[(2*cp+1)*196];
        uint_t pk = (uint_t)f2h(v0) | ((uint_t)f2h(v1) << 16);
        int q = cp >> 2;
        *(uint_t*)&Pt[p*40 + (((q ^ p) & 3) << 3) + ((2*cp) & 7)] = pk;
      }
    }
    #pragma unroll 1
    for (int di = 0; di < 5; ++di){
      __syncthreads();      // Wsm free to overwrite; also fences A writes (di=0)
      // stage W: taps di*5..di*5+4, 64 co x 32 ci fp16 each
      #pragma unroll
      for (int tp = 0; tp < 5; ++tp){
        int tap = di*5 + tp;
        const short8 g = *(const short8*)(Wh + ((size_t)tap*256 + co0 + wco)*256 + cc*32 + wpart*8);
        *(short8*)&Wsm[(tp*64 + wco)*40 + (((wpart ^ wco) & 3) << 3)] = g;
      }
      __syncthreads();
      #pragma unroll
      for (int dj = 0; dj < 5; ++dj){
        half8 a[4], bb[4];
        #pragma unroll
        for (int nt = 0; nt < 4; ++nt){
          int co = nt*16 + mrow;
          bb[nt] = *(const half8*)&Wsm[(dj*64 + co)*40 + (((quad ^ co) & 3) << 3)];
        }
        #pragma unroll
        for (int mt = 0; mt < 4; ++mt){
          int p = prow[mt] + di*20 + dj;
          a[mt] = *(const half8*)&Pt[p*40 + (((quad ^ p) & 3) << 3)];
        }
        #pragma unroll
        for (int mt = 0; mt < 4; ++mt)
          #pragma unroll
          for (int nt = 0; nt < 4; ++nt)
            acc[mt][nt] = __builtin_amdgcn_mfma_f32_16x16x32_f16(a[mt], bb[nt], acc[mt][nt], 0, 0, 0);
      }
    }
  }

  // epilogue: transpose through LDS, then stores into scrambled v5
  #pragma unroll
  for (int hf = 0; hf < 2; ++hf){
    __syncthreads();
    #pragma unroll
    for (int ntl = 0; ntl < 2; ++ntl){
      int nt = hf*2 + ntl;
      int col = ntl*16 + mrow;            // co local within half (0..31)
      #pragma unroll
      for (int mt = 0; mt < 4; ++mt){
        int sbase = wv*64 + mt*16 + quad*4;
        #pragma unroll
        for (int r = 0; r < 4; ++r){
          int s = sbase + r;
          if (s < 196) T[col*200 + s] = acc[mt][nt][r];
        }
      }
    }
    __syncthreads();
    for (int t = tid; t < 6272; t += 256){
      int cl = t / 196;                   // co local 0..31
      int f = (co0 + hf*32)*196 + t;
      float val = T[t + cl*4] + cb[co0 + hf*32 + cl];
      V5[(size_t)b*50176 + (size_t)(f & 255)*196 + (f >> 8)] = val;
    }
  }
}

// ---------- agent token pooling: at = 2x2-mean of q_raw, atk = 2x2-max of k_raw ----------
__global__ __launch_bounds__(256) void k_pool(const float* __restrict__ Y, float* __restrict__ AT, float* __restrict__ ATK){
  int b = blockIdx.x; int c = threadIdx.x;
  const float* qp = Y + ((size_t)b*768 + 512 + c)*196;
  const float* kp = Y + ((size_t)b*768 + c)*196;
  for (int a = 0; a < 49; ++a){
    int p1 = a/7, p2 = a - p1*7;
    int s = p1*28 + p2*2;
    float q0 = qp[s], q1 = qp[s+1], q2 = qp[s+14], q3 = qp[s+15];
    AT[((size_t)b*49 + a)*256 + c] = 0.25f*(q0+q1+q2+q3);
    float k0 = kp[s], k1 = kp[s+1], k2 = kp[s+14], k3 = kp[s+15];
    ATK[((size_t)b*49 + a)*256 + c] = fmaxf(fmaxf(k0,k1), fmaxf(k2,k3));
  }
}

// ---------- cbam stage A: channel gate ----------
__global__ __launch_bounds__(256) void k_cbam_a(const float* __restrict__ V5,
    const float* __restrict__ caa1w, const float* __restrict__ caa1b,
    const float* __restrict__ caa2w, const float* __restrict__ caa2b,
    const float* __restrict__ cam1w, const float* __restrict__ cam1b,
    const float* __restrict__ cam2w, const float* __restrict__ cam2b,
    float* __restrict__ CHG){
  int b = blockIdx.x, c = threadIdx.x;
  __shared__ float avg[256], mx[256], t1[16], t2[16];
  const float* pp = V5 + ((size_t)b*256 + c)*196;
  float s = 0.f, m = -1e30f;
  for (int i = 0; i < 196; ++i){ float v = pp[i]; s += v; m = fmaxf(m, v); }
  avg[c] = s * (1.0f/196.0f); mx[c] = m;
  __syncthreads();
  if (c < 16){
    float a1 = caa1b[c], a2 = cam1b[c];
    #pragma unroll 4
    for (int k = 0; k < 256; ++k){
      a1 = fmaf(caa1w[(c*256 + k)*9 + 4], avg[k], a1);   // 3x3 center tap
      a2 = fmaf(cam1w[c*256 + k], mx[k], a2);            // 1x1
    }
    t1[c] = fmaxf(a1, 0.f);
    t2[c] = fmaxf(a2, 0.f);
  }
  __syncthreads();
  float y1 = caa2b[c], y2 = cam2b[c];
  #pragma unroll
  for (int k = 0; k < 16; ++k){
    y1 = fmaf(caa2w[(c*16 + k)*9 + 4], t1[k], y1);
    y2 = fmaf(cam2w[c*16 + k], t2[k], y2);
  }
  CHG[b*256 + c] = sigmoidf_(sigmoidf_(y1) + sigmoidf_(y2));
}

// ---------- cbam stage B: spatial mask (9x9 pad4 over [mean,max]) + in-place gate ----------
__global__ __launch_bounds__(256) void k_cbam_b(float* __restrict__ V5, const float* __restrict__ CHG,
    const float* __restrict__ saw, const float* __restrict__ sab){
  int b = blockIdx.x; int tid = threadIdx.x;
  __shared__ float chg[256];
  __shared__ float mp[22*22], xp[22*22];
  __shared__ float mk[196];
  chg[tid] = CHG[b*256 + tid];
  for (int t = tid; t < 484; t += 256){ mp[t] = 0.f; xp[t] = 0.f; }
  __syncthreads();
  if (tid < 196){
    int i = tid/14, j = tid - i*14;
    float s = 0.f, m = -1e30f;
    const float* vb = V5 + (size_t)b*256*196 + tid;
    for (int c = 0; c < 256; ++c){
      float v = chg[c] * vb[c*196];
      s += v; m = fmaxf(m, v);
    }
    mp[(i+4)*22 + j+4] = s*(1.f/256.f);
    xp[(i+4)*22 + j+4] = m;
  }
  __syncthreads();
  if (tid < 196){
    int i = tid/14, j = tid - i*14;
    float acc = sab[0];
    for (int di = 0; di < 9; ++di){
      #pragma unroll
      for (int dj = 0; dj < 9; ++dj){
        acc = fmaf(mp[(i+di)*22 + j+dj], saw[di*9+dj], acc);
        acc = fmaf(xp[(i+di)*22 + j+dj], saw[81 + di*9+dj], acc);
      }
    }
    mk[tid] = sigmoidf_(acc);
  }
  __syncthreads();
  if (tid < 196){
    float m = mk[tid];
    float* vb = V5 + (size_t)b*256*196 + tid;
    for (int c = 0; c < 256; ++c) vb[c*196] = chg[c]*vb[c*196]*m;
  }
}

// ---------- big NxN attention; only the per-(b,c) mean of x1 is needed downstream ----------
__global__ __launch_bounds__(256) void k_attn(const float* __restrict__ Y, const float* __restrict__ rpbt,
                                              float* __restrict__ X1S){
  int b = blockIdx.x >> 3, h = blockIdx.x & 7;
  __shared__ float rp[729];
  __shared__ float xs[196*33];
  int tid = threadIdx.x;
  for (int t = tid; t < 729; t += 256) rp[t] = rpbt[t*8 + h];
  __syncthreads();
  const float* yb = Y + (size_t)b*YSTR;
  if (tid < 196){
    int n = tid;
    float q[32];
    {
      const float4* q4 = (const float4*)(yb + QOFF + (size_t)n*256 + h*32);
      #pragma unroll
      for (int u = 0; u < 8; ++u){
        float4 v = q4[u];
        q[4*u] = v.x*SCL; q[4*u+1] = v.y*SCL; q[4*u+2] = v.z*SCL; q[4*u+3] = v.w*SCL;
      }
    }
    int ri = n/14, ci = n - ri*14;
    int bidx = (ri + 13)*27 + (ci + 13);
    float acc[32];
    #pragma unroll
    for (int d = 0; d < 32; ++d) acc[d] = 0.f;
    float l = 0.f;
    int rj = 0, cj = 0;
    for (int j = 0; j < 196; ++j){
      const float4* k4 = (const float4*)(yb + (size_t)j*256 + h*32);
      float s0 = 0.f, s1 = 0.f;
      #pragma unroll
      for (int u = 0; u < 8; u += 2){
        float4 a = k4[u], bb = k4[u+1];
        s0 = fmaf(q[4*u+0],a.x, fmaf(q[4*u+1],a.y, fmaf(q[4*u+2],a.z, fmaf(q[4*u+3],a.w, s0))));
        s1 = fmaf(q[4*u+4],bb.x, fmaf(q[4*u+5],bb.y, fmaf(q[4*u+6],bb.z, fmaf(q[4*u+7],bb.w, s1))));
      }
      float s = s0 + s1 + rp[bidx - rj*27 - cj];
      float p = __expf(s);       // logits are O(0.1): max-free softmax is safe
      l += p;
      const float4* v4 = (const float4*)(yb + VOFF + (size_t)j*256 + h*32);
      #pragma unroll
      for (int u = 0; u < 8; ++u){
        float4 vv = v4[u];
        acc[4*u]   = fmaf(p, vv.x, acc[4*u]);
        acc[4*u+1] = fmaf(p, vv.y, acc[4*u+1]);
        acc[4*u+2] = fmaf(p, vv.z, acc[4*u+2]);
        acc[4*u+3] = fmaf(p, vv.w, acc[4*u+3]);
      }
      if (++cj == 14){ cj = 0; ++rj; }
    }
    float inv = 1.f/l;
    #pragma unroll
    for (int d = 0; d < 32; ++d) xs[n*33 + d] = acc[d]*inv;
  }
  __syncthreads();
  if (tid < 32){
    float s = 0.f;
    for (int n = 0; n < 196; ++n) s += xs[n*33 + tid];
    X1S[(size_t)b*256 + h*32 + tid] = s*(1.f/196.f);   // mean over n of x1[b,:,c]
  }
}

// ---------- chan_inter on x1 mean -> sigmoid gate CMAP ----------
__global__ __launch_bounds__(256) void k_cinter(const float* __restrict__ X1S,
    const float* __restrict__ ci1w, const float* __restrict__ ci1b,
    const float* __restrict__ bng, const float* __restrict__ bnb,
    const float* __restrict__ ci2w, const float* __restrict__ ci2b, float* __restrict__ CMAP){
  int b = blockIdx.x, c = threadIdx.x;
  __shared__ float p[256], tt[16];
  p[c] = X1S[b*256 + c];
  __syncthreads();
  if (c < 16){
    float a = ci1b[c];
    #pragma unroll 4
    for (int k = 0; k < 256; ++k) a = fmaf(ci1w[(c*256+k)*25 + 12], p[k], a);  // 5x5 center
    const float invs = 0.9999950000375f;   // 1/sqrt(1+1e-5)
    tt[c] = fmaxf(fmaf(bng[c]*invs, a, bnb[c]), 0.f);
  }
  __syncthreads();
  float a = ci2b[c];
  #pragma unroll
  for (int k = 0; k < 16; ++k) a = fmaf(ci2w[(c*16+k)*25 + 12], tt[k], a);
  CMAP[b*256 + c] = sigmoidf_(a);
}

// ---------- agent_v: merged q/k passes, fp16 score buffers, 4 blocks/CU ----------
// agent_v = softmax(at*scale@K^T+pb)@V1 + softmax(atk*scale@Q^T+pb)@V.
// Lane = agent (49 of 64), wave = d-octet for PV. One logits loop computes
// both score matrices (16 indep uniform b128 loads/iter); one PV loop reads
// both V sources. S0/S1 are fp16 in LDS (40.4 KB total -> 4 blocks/CU).
__global__ __launch_bounds__(256) void k_agentv(const float* __restrict__ Y, const float* __restrict__ V5,
    const float* __restrict__ AT, const float* __restrict__ ATK,
    const float* __restrict__ PBT, float* __restrict__ AGV){
  int b = blockIdx.x >> 3, h = blockIdx.x & 7;
  __shared__ ushort_t S0[196*49];   // exp(agent_attn logits) fp16, [n][a]
  __shared__ ushort_t S1[196*49];   // exp(agent_attn1 logits)
  __shared__ float2 part[4*64];     // per-wave (sum0, sum1) per agent
  int tid = threadIdx.x;
  int wv = tid >> 6, lane = tid & 63;
  const float* yb = Y + (size_t)b*YSTR;
  float ar[32], akr[32];
  if (lane < 49){
    const float4* ap = (const float4*)(AT  + ((size_t)b*49 + lane)*256 + h*32);
    const float4* kp = (const float4*)(ATK + ((size_t)b*49 + lane)*256 + h*32);
    #pragma unroll
    for (int u = 0; u < 8; ++u){
      float4 a = ap[u], k = kp[u];
      ar[4*u]=a.x; ar[4*u+1]=a.y; ar[4*u+2]=a.z; ar[4*u+3]=a.w;
      akr[4*u]=k.x; akr[4*u+1]=k.y; akr[4*u+2]=k.z; akr[4*u+3]=k.w;
    }
  }
  // ---- merged logits: s0 = (ar.K[n])*SCL + pb ; s1 = (akr.Q[n])*SCL^2 + pb ----
  float l0 = 0.f, l1 = 0.f;
  if (lane < 49){
    for (int n = wv; n < 196; n += 4){
      const float4* k4 = (const float4*)(yb + (size_t)n*256 + h*32);
      const float4* q4 = (const float4*)(yb + QOFF + (size_t)n*256 + h*32);
      float s0 = 0.f, s1 = 0.f;
      #pragma unroll
      for (int u = 0; u < 8; ++u){
        float4 kv = k4[u], qv = q4[u];
        s0 = fmaf(ar[4*u],kv.x, fmaf(ar[4*u+1],kv.y, fmaf(ar[4*u+2],kv.z, fmaf(ar[4*u+3],kv.w, s0))));
        s1 = fmaf(akr[4*u],qv.x, fmaf(akr[4*u+1],qv.y, fmaf(akr[4*u+2],qv.z, fmaf(akr[4*u+3],qv.w, s1))));
      }
      float pb = PBT[((size_t)h*196 + n)*49 + lane];
      ushort_t e0 = f2h(__expf(fmaf(s0, SCL, pb)));
      ushort_t e1 = f2h(__expf(fmaf(s1, 0.03125f, pb)));
      S0[n*49 + lane] = e0;
      S1[n*49 + lane] = e1;
      l0 += h2f(e0);               // sum the quantized values for consistency
      l1 += h2f(e1);
    }
  }
  part[wv*64 + lane] = make_float2(l0, l1);
  __syncthreads();
  // ---- merged PV ----
  if (lane < 49){
    float2 p0 = part[lane], p1 = part[64+lane], p2 = part[128+lane], p3 = part[192+lane];
    float inv0 = 1.f/(p0.x + p1.x + p2.x + p3.x);
    float inv1 = 1.f/(p0.y + p1.y + p2.y + p3.y);
    int d0 = wv*8;
    float acc0[8], acc1[8];
    #pragma unroll
    for (int d = 0; d < 8; ++d){ acc0[d] = 0.f; acc1[d] = 0.f; }
    const float* v0p = V5 + (size_t)b*50176 + (h*32 + d0)*196;   // [r][196]
    const float* v1p = yb + VOFF + h*32 + d0;                    // [n][8] contiguous
    for (int n = 0; n < 196; ++n){
      float pv0 = h2f(S0[n*49 + lane]);
      float pv1 = h2f(S1[n*49 + lane]);
      #pragma unroll
      for (int r = 0; r < 8; ++r) acc0[r] = fmaf(pv0, v0p[r*196 + n], acc0[r]);
      const float4* vv = (const float4*)(v1p + (size_t)n*256);
      float4 va = vv[0], vb2 = vv[1];
      acc1[0] = fmaf(pv1, va.x,  acc1[0]);
      acc1[1] = fmaf(pv1, va.y,  acc1[1]);
      acc1[2] = fmaf(pv1, va.z,  acc1[2]);
      acc1[3] = fmaf(pv1, va.w,  acc1[3]);
      acc1[4] = fmaf(pv1, vb2.x, acc1[4]);
      acc1[5] = fmaf(pv1, vb2.y, acc1[5]);
      acc1[6] = fmaf(pv1, vb2.z, acc1[6]);
      acc1[7] = fmaf(pv1, vb2.w, acc1[7]);
    }
    float* dst = AGV + (((size_t)(b*8 + h)*49) + lane)*32 + d0;
    #pragma unroll
    for (int d = 0; d < 8; ++d) dst[d] = acc0[d]*inv0 + acc1[d]*inv1;
  }
}

// ---------- xo1 = (softmax(q*scale@at^T+ab) + softmax(k*scale@atk^T+ab)) @ agent_v ----------
__global__ __launch_bounds__(256) void k_xo1(const float* __restrict__ Y,
    const float* __restrict__ AT, const float* __restrict__ ATK,
    const float* __restrict__ AB, const float* __restrict__ AGV, float* __restrict__ XO){
  int b = blockIdx.x >> 3, h = blockIdx.x & 7;
  __shared__ float P[98*53];
  __shared__ float sAGV[49*32];
  int tid = threadIdx.x;
  int wv = tid >> 6, lane = tid & 63;
  const float* yb = Y + (size_t)b*YSTR;
  float ar[32], akr[32];
  if (lane < 49){
    const float4* ap = (const float4*)(AT  + ((size_t)b*49 + lane)*256 + h*32);
    const float4* kp = (const float4*)(ATK + ((size_t)b*49 + lane)*256 + h*32);
    #pragma unroll
    for (int u = 0; u < 8; ++u){
      float4 a = ap[u], k = kp[u];
      ar[4*u]=a.x; ar[4*u+1]=a.y; ar[4*u+2]=a.z; ar[4*u+3]=a.w;
      akr[4*u]=k.x; akr[4*u+1]=k.y; akr[4*u+2]=k.z; akr[4*u+3]=k.w;
    }
  }
  {
    const float* agvb = AGV + (size_t)(b*8 + h)*49*32;
    for (int t = tid; t < 1568; t += 256) sAGV[t] = agvb[t];
  }
  #pragma unroll 1
  for (int chunk = 0; chunk < 2; ++chunk){
    __syncthreads();    // P safe to overwrite; (chunk 0: also fences sAGV stores)
    for (int i = wv; i < 98; i += 4){
      int n = chunk*98 + i;
      float eq = 0.f, ek = 0.f;
      if (lane < 49){
        float ab = AB[((size_t)h*196 + n)*49 + lane];
        const float4* q4 = (const float4*)(yb + QOFF + (size_t)n*256 + h*32);
        const float4* k4 = (const float4*)(yb + (size_t)n*256 + h*32);
        float sq = 0.f, sk = 0.f;
        #pragma unroll
        for (int u = 0; u < 8; ++u){
          float4 qv = q4[u], kv = k4[u];
          sq = fmaf(ar[4*u],qv.x, fmaf(ar[4*u+1],qv.y, fmaf(ar[4*u+2],qv.z, fmaf(ar[4*u+3],qv.w, sq))));
          sk = fmaf(akr[4*u],kv.x, fmaf(akr[4*u+1],kv.y, fmaf(akr[4*u+2],kv.z, fmaf(akr[4*u+3],kv.w, sk))));
        }
        eq = __expf(fmaf(sq, 0.03125f, ab));   // (q*scale . at*scale)
        ek = __expf(fmaf(sk, SCL, ab));        // (k*scale . atk)
      }
      float tq = eq, tk = ek;
      #pragma unroll
      for (int o = 32; o > 0; o >>= 1){ tq += __shfl_xor(tq, o); tk += __shfl_xor(tk, o); }
      if (lane < 49) P[i*53 + lane] = eq/tq + ek/tk;
    }
    __syncthreads();
    if (tid < 196){
      int i = tid >> 1, dh = tid & 1;      // row i, d half
      int n = chunk*98 + i;
      float out[16];
      #pragma unroll
      for (int d = 0; d < 16; ++d) out[d] = 0.f;
      const float* pr = &P[i*53];
      #pragma unroll 7
      for (int a = 0; a < 49; ++a){
        float pv = pr[a];
        const float4* g4 = (const float4*)&sAGV[a*32 + dh*16];
        #pragma unroll
        for (int u = 0; u < 4; ++u){
          float4 gv = g4[u];
          out[4*u]   = fmaf(pv, gv.x, out[4*u]);
          out[4*u+1] = fmaf(pv, gv.y, out[4*u+1]);
          out[4*u+2] = fmaf(pv, gv.z, out[4*u+2]);
          out[4*u+3] = fmaf(pv, gv.w, out[4*u+3]);
        }
      }
      float* dst = XO + ((size_t)b*196 + n)*256 + h*32 + dh*16;
      #pragma unroll
      for (int d = 0; d < 16; ++d) dst[d] = out[d];
    }
  }
}

// ---------- fused depthwise conv: dwc(conv_x2 + qc), bias 2*dwc_b, accumulated into XO ----------
__global__ __launch_bounds__(256) void k_dwc(const float* __restrict__ Y, const float* __restrict__ CMAP,
    const float* __restrict__ dw, const float* __restrict__ db, float* __restrict__ XO){
  int b = blockIdx.x >> 3, cg = blockIdx.x & 7;
  int c0 = cg*32;
  __shared__ __align__(16) float pl[32*360];
  int tid = threadIdx.x;
  for (int t = tid; t < 32*360; t += 256) pl[t] = 0.f;
  __syncthreads();
  const float* yq = Y + (size_t)b*YSTR + QOFF;
  for (int t = tid; t < 32*196; t += 256){
    int cl = t & 31, s = t >> 5;
    int c = c0 + cl;
    int G = s*256 + c;                 // head-major flat index for conv_x2's scramble
    int hh = G / 6272;
    int rem = G - hh*6272;
    int n = rem >> 5, d = rem & 31;
    float cx2 = CMAP[b*256 + c] * yq[n*256 + hh*32 + d];   // sigmoid(cmap)*qs
    float qc  = yq[G];                                     // qc collapses to identity gather
    float v = SCL*(cx2 + qc);
    int i = s/14, j = s - i*14;
    pl[cl*360 + (i+2)*20 + j + 2] = v;
  }
  __syncthreads();
  for (int t = tid; t < 32*14; t += 256){
    int cl = t/14, r = t - cl*14;
    int c = c0 + cl;
    float w25[25];
    #pragma unroll
    for (int u = 0; u < 25; ++u) w25[u] = dw[c*25 + u];
    float acc[14];
    float b2 = 2.f*db[c];
    #pragma unroll
    for (int j = 0; j < 14; ++j) acc[j] = b2;
    conv5x5_row(&pl[cl*360], r, w25, acc);
    float* dst = XO + ((size_t)b*196 + r*14)*256 + c;
    #pragma unroll
    for (int j = 0; j < 14; ++j) dst[j*256] += acc[j];
  }
}

// ---------- final projection: out = XO @ proj_w^T + proj_b ----------
__global__ __launch_bounds__(256) void k_proj(const float* __restrict__ XO, const float* __restrict__ WT,
    const float* __restrict__ pbias, float* __restrict__ OUT){
  int bb = blockIdx.x / 7, nt = blockIdx.x % 7;
  int n0 = nt*28;
  int c = threadIdx.x;
  const float* xb = XO + ((size_t)bb*196 + n0)*256;
  float acc[28];
  #pragma unroll
  for (int r = 0; r < 28; ++r) acc[r] = 0.f;
  for (int k = 0; k < 256; k += 4){
    float w0 = WT[(k+0)*256 + c];
    float w1 = WT[(k+1)*256 + c];
    float w2 = WT[(k+2)*256 + c];
    float w3 = WT[(k+3)*256 + c];
    #pragma unroll
    for (int r = 0; r < 28; ++r){
      float4 xv = *(const float4*)(xb + r*256 + k);   // uniform address -> scalar/L1 path
      acc[r] = fmaf(xv.x, w0, fmaf(xv.y, w1, fmaf(xv.z, w2, fmaf(xv.w, w3, acc[r]))));
    }
  }
  float bv = pbias[c];
  float* dst = OUT + ((size_t)bb*196 + n0)*256 + c;
  #pragma unroll
  for (int r = 0; r < 28; ++r) dst[r*256] = acc[r] + bv;
}

extern "C" void kernel_launch(void* const* d_in, const int* in_sizes, int n_in,
                              void* d_out, int out_size, void* d_ws, size_t ws_size,
                              hipStream_t stream){
  (void)in_sizes; (void)n_in; (void)out_size; (void)ws_size;
  const float* x       = (const float*)d_in[0];
  const float* lka_w   = (const float*)d_in[3];
  const float* lka_b   = (const float*)d_in[4];
  const float* conv5_w = (const float*)d_in[5];
  const float* conv5_b = (const float*)d_in[6];
  const float* caa1_w  = (const float*)d_in[7];
  const float* caa1_b  = (const float*)d_in[8];
  const float* caa2_w  = (const float*)d_in[9];
  const float* caa2_b  = (const float*)d_in[10];
  const float* cam1_w  = (const float*)d_in[11];
  const float* cam1_b  = (const float*)d_in[12];
  const float* cam2_w  = (const float*)d_in[13];
  const float* cam2_b  = (const float*)d_in[14];
  const float* sa_w    = (const float*)d_in[15];
  const float* sa_b    = (const float*)d_in[16];
  const float* ci1_w   = (const float*)d_in[17];
  const float* ci1_b   = (const float*)d_in[18];
  const float* bn_g    = (const float*)d_in[19];
  const float* bn_b    = (const float*)d_in[20];
  const float* ci2_w   = (const float*)d_in[21];
  const float* ci2_b   = (const float*)d_in[22];
  const float* rpbt    = (const float*)d_in[23];
  const float* an_bias = (const float*)d_in[24];
  const float* na_bias = (const float*)d_in[25];
  const float* ah_bias = (const float*)d_in[26];
  const float* aw_bias = (const float*)d_in[27];
  const float* ha_bias = (const float*)d_in[28];
  const float* wa_bias = (const float*)d_in[29];
  const float* dwc_w   = (const float*)d_in[30];
  const float* dwc_b   = (const float*)d_in[31];
  const float* proj_w  = (const float*)d_in[32];
  const float* proj_b  = (const float*)d_in[33];
  float* out = (float*)d_out;
  float* ws = (float*)d_ws;

  float* Y    = ws + WS_Y;
  float* V5   = ws + WS_V5;
  float* AT   = ws + WS_AT;
  float* ATK  = ws + WS_ATK;
  float* CHG  = ws + WS_CHG;
  float* CMAP = ws + WS_CMAP;
  float* PBT  = ws + WS_PBT;
  float* AB   = ws + WS_AB;
  float* X1S  = ws + WS_X1S;
  float* AGV  = ws + WS_AGV;
  float* XO   = ws + WS_XO;
  float* WT   = ws + WS_WT;
  ushort_t* Wh = (ushort_t*)(ws + WS_CWT);

  k_pb   <<<301, 256, 0, stream>>>(an_bias, ah_bias, aw_bias, PBT);
  k_ab   <<<301, 256, 0, stream>>>(na_bias, ha_bias, wa_bias, AB);
  k_wt   <<<256, 256, 0, stream>>>(proj_w, WT);
  k_cw2  <<<6400, 256, 0, stream>>>(conv5_w, Wh);
  k_lka  <<<1024, 256, 0, stream>>>(x, lka_w, lka_b, Y);
  k_conv5<<<512, 256, 0, stream>>>(Y, Wh, conv5_b, V5);
  k_pool <<<128, 256, 0, stream>>>(Y, AT, ATK);
  k_cbam_a<<<128, 256, 0, stream>>>(V5, caa1_w, caa1_b, caa2_w, caa2_b,
                                    cam1_w, cam1_b, cam2_w, cam2_b, CHG);
  k_cbam_b<<<128, 256, 0, stream>>>(V5, CHG, sa_w, sa_b);
  k_attn <<<1024, 256, 0, stream>>>(Y, rpbt, X1S);
  k_cinter<<<128, 256, 0, stream>>>(X1S, ci1_w, ci1_b, bn_g, bn_b, ci2_w, ci2_b, CMAP);
  k_agentv<<<1024, 256, 0, stream>>>(Y, V5, AT, ATK, PBT, AGV);
  k_xo1  <<<1024, 256, 0, stream>>>(Y, AT, ATK, AB, AGV, XO);
  k_dwc  <<<1024, 256, 0, stream>>>(Y, CMAP, dwc_w, dwc_b, XO);
  k_proj <<<896, 256, 0, stream>>>(XO, WT, proj_b, out);
}